// Round 10
// baseline (225.195 us; speedup 1.0000x reference)
//
#include <hip/hip_runtime.h>
#include <math.h>

#define L2E 1.44269504088896f
#define LRELU(v) fmaxf((v), 0.2f * (v))

__device__ __forceinline__ float fexp2(float v) { return __builtin_amdgcn_exp2f(v); }

// bf16 helpers (RNE pack, exact unpack)
__device__ __forceinline__ unsigned short f2bf(float f) {
    unsigned u = __float_as_uint(f);
    u += 0x7FFFu + ((u >> 16) & 1u);
    return (unsigned short)(u >> 16);
}
__device__ __forceinline__ float bf2f(unsigned short b) {
    return __uint_as_float((unsigned)b << 16);
}

// base-2 online-softmax update, 4 channels (float4 acc)
#define UPD4(mm, dd, AA, ev, GG)           \
    {                                      \
        float mn_ = fmaxf(mm, ev);         \
        float sc_ = fexp2(mm - mn_);       \
        float w_  = fexp2(ev - mn_);       \
        dd = dd * sc_ + w_;                \
        AA.x = AA.x * sc_ + w_ * (GG).x;   \
        AA.y = AA.y * sc_ + w_ * (GG).y;   \
        AA.z = AA.z * sc_ + w_ * (GG).z;   \
        AA.w = AA.w * sc_ + w_ * (GG).w;   \
        mm = mn_;                          \
    }
#define UPD1(mm, dd, aa, ev, hv)           \
    {                                      \
        float mn_ = fmaxf(mm, ev);         \
        float sc_ = fexp2(mm - mn_);       \
        float w_  = fexp2(ev - mn_);       \
        dd = dd * sc_ + w_;                \
        aa = aa * sc_ + w_ * (hv);         \
        mm = mn_;                          \
    }

#define CH 4096   // edges per bucket-build block

__device__ __forceinline__ float4 b4f(ushort4 u) {
    float4 r;
    r.x = bf2f(u.x); r.y = bf2f(u.y); r.z = bf2f(u.z); r.w = bf2f(u.w);
    return r;
}

// ---------------- layer-1 GEMM: x-tile in LDS (transposed), W via scalar loads ----------------
// Block = 256 threads = 4 waves; 64 nodes/block (lane = node).
// Wave w computes cols 16w..16w+15 (heads 2w, 2w+1). W address is wave-uniform -> SGPR.
__global__ __launch_bounds__(256) void k_gemm1(
        const float* __restrict__ x, const float* __restrict__ W,
        const float* __restrict__ a_src, const float* __restrict__ a_dst,
        unsigned short* __restrict__ h1b, unsigned short* __restrict__ asrcb,
        float* __restrict__ adst, int N) {
    __shared__ float xl[128 * 65];    // [k][node], pad 65 -> conflict-free both ways
    int tid = threadIdx.x;
    int n0 = blockIdx.x * 64;
    int nrem = N - n0;                // >=1 by grid construction
    // stage: 8192 coalesced scalar loads, transposed scatter into LDS
#pragma unroll
    for (int i = 0; i < 32; ++i) {
        int e = i * 256 + tid;        // 0..8191
        int row = e >> 7, k = e & 127;
        float v = (row < nrem) ? x[(size_t)(n0 + row) * 128 + k] : 0.f;
        xl[k * 65 + row] = v;
    }
    __syncthreads();

    int wv = tid >> 6, lane = tid & 63;
    int c0 = __builtin_amdgcn_readfirstlane(wv * 16);
    const float* Wc = W + c0;         // uniform base -> scalar loads in loop

    float acc[16];
#pragma unroll
    for (int c = 0; c < 16; ++c) acc[c] = 0.f;

#pragma unroll 4
    for (int k = 0; k < 128; ++k) {
        float xv = xl[k * 65 + lane];
#pragma unroll
        for (int c = 0; c < 16; ++c)
            acc[c] = fmaf(xv, Wc[k * 64 + c], acc[c]);
    }

    int n = n0 + lane;
    if (n >= N) return;
    // epilogue: alpha dots for heads h0 = 2w (cols c0..c0+7) and h0+1 (c0+8..c0+15)
    int h0 = c0 >> 3;
    float s0 = 0.f, d0 = 0.f, s1 = 0.f, d1 = 0.f;
    uint4 pk0, pk1;
    unsigned* p0 = (unsigned*)&pk0;
    unsigned* p1 = (unsigned*)&pk1;
#pragma unroll
    for (int c = 0; c < 8; c += 2) {
        s0 = fmaf(acc[c], a_src[c0 + c], s0);       d0 = fmaf(acc[c], a_dst[c0 + c], d0);
        s0 = fmaf(acc[c+1], a_src[c0 + c + 1], s0); d0 = fmaf(acc[c+1], a_dst[c0 + c + 1], d0);
        p0[c >> 1] = (unsigned)f2bf(acc[c]) | ((unsigned)f2bf(acc[c+1]) << 16);
    }
#pragma unroll
    for (int c = 8; c < 16; c += 2) {
        s1 = fmaf(acc[c], a_src[c0 + c], s1);       d1 = fmaf(acc[c], a_dst[c0 + c], d1);
        s1 = fmaf(acc[c+1], a_src[c0 + c + 1], s1); d1 = fmaf(acc[c+1], a_dst[c0 + c + 1], d1);
        p1[(c - 8) >> 1] = (unsigned)f2bf(acc[c]) | ((unsigned)f2bf(acc[c+1]) << 16);
    }
    *(uint4*)&h1b[(size_t)n * 64 + c0] = pk0;
    *(uint4*)&h1b[(size_t)n * 64 + c0 + 8] = pk1;
    asrcb[n * 8 + h0]     = f2bf(s0 * L2E);
    asrcb[n * 8 + h0 + 1] = f2bf(s1 * L2E);
    adst[n * 8 + h0]      = d0 * L2E;
    adst[n * 8 + h0 + 1]  = d1 * L2E;
}

// ---------------- graph-bucket sort (zero global atomics) ----------------

__global__ __launch_bounds__(256) void k_bhist(const int* __restrict__ dstE,
                                               const int* __restrict__ batch,
                                               int E, int NB, int G, int* __restrict__ bh) {
    __shared__ int lh[512];
    int tid = threadIdx.x, b = blockIdx.x;
    lh[tid] = 0; lh[tid + 256] = 0;
    __syncthreads();
#pragma unroll
    for (int i = 0; i < CH / 256; ++i) {
        int e = b * CH + i * 256 + tid;
        if (e < E) atomicAdd(&lh[batch[dstE[e]]], 1);
    }
    __syncthreads();
    if (tid < G)       bh[(size_t)tid * NB + b] = lh[tid];
    if (tid + 256 < G) bh[(size_t)(tid + 256) * NB + b] = lh[tid + 256];
}

__global__ __launch_bounds__(512) void k_mscan(const int* __restrict__ bh, int NB,
                                               int* __restrict__ pstart, int* __restrict__ total) {
    __shared__ int buf[512];
    int bin = blockIdx.x, t = threadIdx.x;
    int v = (t < NB) ? bh[(size_t)bin * NB + t] : 0;
    buf[t] = v;
    __syncthreads();
    for (int off = 1; off < 512; off <<= 1) {
        int u = (t >= off) ? buf[t - off] : 0;
        __syncthreads();
        buf[t] += u;
        __syncthreads();
    }
    if (t < NB) pstart[(size_t)bin * NB + t] = buf[t] - v;
    if (t == 511) total[bin] = buf[511];
}

__global__ __launch_bounds__(1024) void k_scan_top(const int* __restrict__ total, int nb,
                                                   int* __restrict__ boff) {
    __shared__ int buf[1024];
    int t = threadIdx.x;
    int v = (t < nb) ? total[t] : 0;
    buf[t] = v;
    __syncthreads();
    for (int off = 1; off < 1024; off <<= 1) {
        int u = (t >= off) ? buf[t - off] : 0;
        __syncthreads();
        buf[t] += u;
        __syncthreads();
    }
    if (t < nb) boff[t] = buf[t] - v;
}

__global__ __launch_bounds__(256) void k_bscatter(const int* __restrict__ srcE,
                                                  const int* __restrict__ dstE,
                                                  const int* __restrict__ batch,
                                                  const int* __restrict__ boff,
                                                  const int* __restrict__ pstart,
                                                  int E, int NB, int G, int2* __restrict__ pairs) {
    __shared__ int lstart[512];
    __shared__ int lc[512];
    int tid = threadIdx.x, b = blockIdx.x;
#pragma unroll
    for (int j = tid; j < 512; j += 256) {
        lstart[j] = (j < G) ? boff[j] + pstart[(size_t)j * NB + b] : 0;
        lc[j] = 0;
    }
    __syncthreads();
#pragma unroll
    for (int i = 0; i < CH / 256; ++i) {
        int e = b * CH + i * 256 + tid;
        if (e < E) {
            int s = srcE[e], d = dstE[e];
            int bin = batch[d];
            int old = atomicAdd(&lc[bin], 1);
            pairs[lstart[bin] + old] = make_int2(s, d);
        }
    }
}

__global__ __launch_bounds__(512) void k_csr_local(const int2* __restrict__ pairs,
                                                   const int* __restrict__ boff,
                                                   const int* __restrict__ batch,
                                                   int E, int N, int G,
                                                   int* __restrict__ cnt, int* __restrict__ excl,
                                                   int* __restrict__ srcs) {
    __shared__ int lcnt[512];
    __shared__ int buf[512];
    __shared__ int lcur[512];
    int g = blockIdx.x, t = threadIdx.x;
    int lo = 0, hi = N;
    while (lo < hi) { int mid = (lo + hi) >> 1; if (batch[mid] < g) lo = mid + 1; else hi = mid; }
    int ns = lo;
    hi = N;
    while (lo < hi) { int mid = (lo + hi) >> 1; if (batch[mid] < g + 1) lo = mid + 1; else hi = mid; }
    int ne = lo;
    int lnodes = ne - ns;
    int es = boff[g];
    int ee = (g + 1 < G) ? boff[g + 1] : E;

    lcnt[t] = 0;
    __syncthreads();
    for (int e = es + t; e < ee; e += 512) atomicAdd(&lcnt[pairs[e].y - ns], 1);
    __syncthreads();
    int v = lcnt[t];
    buf[t] = v;
    __syncthreads();
    for (int off = 1; off < 512; off <<= 1) {
        int u = (t >= off) ? buf[t - off] : 0;
        __syncthreads();
        buf[t] += u;
        __syncthreads();
    }
    int lex = buf[t] - v;
    lcur[t] = lex;
    if (t < lnodes) {
        cnt[ns + t] = v;
        excl[ns + t] = es + lex;
    }
    __syncthreads();
    for (int e = es + t; e < ee; e += 512) {
        int2 p = pairs[e];
        int pos = atomicAdd(&lcur[p.y - ns], 1);
        srcs[es + pos] = p.x;
    }
}

// ---------------- layer 1 gather: 4 nodes/wave, 16 lanes/node, bf16x4/lane ----------------
__global__ void k_gather1(const int* __restrict__ srcs, const int* __restrict__ excl,
                          const int* __restrict__ cnt,
                          const unsigned short* __restrict__ asrcb, const float* __restrict__ adst1,
                          const unsigned short* __restrict__ h1b, float* __restrict__ agg, int N) {
    int tid = blockIdx.x * 256 + threadIdx.x;
    int wave = tid >> 6;
    int lane = threadIdx.x & 63;
    int q = lane >> 4;            // node slot
    int l = lane & 15;
    int wid = wave * 4 + q;
    if (wid >= N) return;
    int h = l >> 1;               // head (2 lanes/head)
    int c0 = l * 4;               // channels c0..c0+3

    int beg = excl[wid];
    int cw  = cnt[wid];
    const int* sp = srcs + beg;
    float adh = adst1[wid * 8 + h];

    // self-loop init on chain 0
    float4 A0 = b4f(*(const ushort4*)&h1b[(size_t)wid * 64 + c0]);
    float m0 = LRELU(bf2f(asrcb[wid * 8 + h]) + adh), d0 = 1.f;
    float4 A1 = {0.f, 0.f, 0.f, 0.f}, A2 = A1, A3 = A1;
    float m1 = -INFINITY, d1 = 0.f;
    float m2 = -INFINITY, d2 = 0.f;
    float m3 = -INFINITY, d3 = 0.f;

    int i = 0;
    for (; i + 4 <= cw; i += 4) {
        int s0 = sp[i], s1 = sp[i + 1], s2 = sp[i + 2], s3 = sp[i + 3];
        float e0 = LRELU(bf2f(asrcb[s0 * 8 + h]) + adh);
        float e1 = LRELU(bf2f(asrcb[s1 * 8 + h]) + adh);
        float e2 = LRELU(bf2f(asrcb[s2 * 8 + h]) + adh);
        float e3 = LRELU(bf2f(asrcb[s3 * 8 + h]) + adh);
        float4 g0 = b4f(*(const ushort4*)&h1b[(size_t)s0 * 64 + c0]);
        float4 g1 = b4f(*(const ushort4*)&h1b[(size_t)s1 * 64 + c0]);
        float4 g2 = b4f(*(const ushort4*)&h1b[(size_t)s2 * 64 + c0]);
        float4 g3 = b4f(*(const ushort4*)&h1b[(size_t)s3 * 64 + c0]);
        UPD4(m0, d0, A0, e0, g0);
        UPD4(m1, d1, A1, e1, g1);
        UPD4(m2, d2, A2, e2, g2);
        UPD4(m3, d3, A3, e3, g3);
    }
    for (; i < cw; ++i) {
        int s = sp[i];
        float ev = LRELU(bf2f(asrcb[s * 8 + h]) + adh);
        float4 gv = b4f(*(const ushort4*)&h1b[(size_t)s * 64 + c0]);
        UPD4(m0, d0, A0, ev, gv);
    }
    float mM = fmaxf(fmaxf(m0, m1), fmaxf(m2, m3));
    float w0 = fexp2(m0 - mM), w1 = fexp2(m1 - mM);
    float w2 = fexp2(m2 - mM), w3 = fexp2(m3 - mM);
    float den = d0 * w0 + d1 * w1 + d2 * w2 + d3 * w3;
    float inv = 1.f / (den + 1e-16f);
    float4 r;
    r.x = (A0.x * w0 + A1.x * w1 + A2.x * w2 + A3.x * w3) * inv;
    r.y = (A0.y * w0 + A1.y * w1 + A2.y * w2 + A3.y * w3) * inv;
    r.z = (A0.z * w0 + A1.z * w1 + A2.z * w2 + A3.z * w3) * inv;
    r.w = (A0.w * w0 + A1.w * w1 + A2.w * w2 + A3.w * w3) * inv;
    *(float4*)&agg[(size_t)wid * 64 + c0] = r;
}

// out1 = elu(agg + b1); h2 = out1 @ W2 (64x10) -> bf16; layer-2 alpha dots (x log2e)
__global__ void k_fin1(const float* __restrict__ agg, const float* __restrict__ b1,
                       const float* __restrict__ W2,
                       const float* __restrict__ a_src2, const float* __restrict__ a_dst2,
                       unsigned short* __restrict__ h2b, unsigned short* __restrict__ asrc2b,
                       float* __restrict__ adst2, int N) {
    int n = blockIdx.x * 256 + threadIdx.x;
    if (n >= N) return;
    float acc[10];
#pragma unroll
    for (int j = 0; j < 10; ++j) acc[j] = 0.f;
    const float* ar = agg + (size_t)n * 64;
#pragma unroll 8
    for (int k = 0; k < 64; ++k) {
        float r = ar[k] + b1[k];
        r = r > 0.f ? r : expm1f(r);   // elu
#pragma unroll
        for (int j = 0; j < 10; ++j) acc[j] = fmaf(r, W2[k * 10 + j], acc[j]);
    }
    float s = 0.f, d = 0.f;
    unsigned pw[5];
#pragma unroll
    for (int j = 0; j < 10; j += 2) {
        s = fmaf(acc[j], a_src2[j], s);     d = fmaf(acc[j], a_dst2[j], d);
        s = fmaf(acc[j+1], a_src2[j+1], s); d = fmaf(acc[j+1], a_dst2[j+1], d);
        pw[j >> 1] = (unsigned)f2bf(acc[j]) | ((unsigned)f2bf(acc[j+1]) << 16);
    }
    unsigned* hw = (unsigned*)&h2b[(size_t)n * 10];
#pragma unroll
    for (int j = 0; j < 5; ++j) hw[j] = pw[j];
    asrc2b[n] = f2bf(s * L2E);
    adst2[n] = d * L2E;
}

// ---------------- layer 2 gather: 4 nodes/wave, 16 lanes/node ----------------
__global__ void k_gather2(const int* __restrict__ srcs, const int* __restrict__ excl,
                          const int* __restrict__ cnt,
                          const unsigned short* __restrict__ asrc2b, const float* __restrict__ adst2,
                          const unsigned short* __restrict__ h2b, float* __restrict__ agg2, int N) {
    int tid = blockIdx.x * 256 + threadIdx.x;
    int wave = tid >> 6;
    int lane = threadIdx.x & 63;
    int q = lane >> 4;
    int l = lane & 15;
    int wid = wave * 4 + q;
    if (wid >= N) return;

    int beg = excl[wid];
    int cw  = cnt[wid];
    const int* sp = srcs + beg;
    float adn = adst2[wid];
    bool ld = l < 10;

    float m0 = LRELU(bf2f(asrc2b[wid]) + adn), d0 = 1.f;
    float a0 = ld ? bf2f(h2b[(size_t)wid * 10 + l]) : 0.f;
    float m1 = -INFINITY, d1 = 0.f, a1 = 0.f;
    float m2 = -INFINITY, d2 = 0.f, a2 = 0.f;
    float m3 = -INFINITY, d3 = 0.f, a3 = 0.f;

    int i = 0;
    for (; i + 4 <= cw; i += 4) {
        int s0 = sp[i], s1 = sp[i + 1], s2 = sp[i + 2], s3 = sp[i + 3];
        float e0 = LRELU(bf2f(asrc2b[s0]) + adn);
        float e1 = LRELU(bf2f(asrc2b[s1]) + adn);
        float e2 = LRELU(bf2f(asrc2b[s2]) + adn);
        float e3 = LRELU(bf2f(asrc2b[s3]) + adn);
        float g0 = ld ? bf2f(h2b[(size_t)s0 * 10 + l]) : 0.f;
        float g1 = ld ? bf2f(h2b[(size_t)s1 * 10 + l]) : 0.f;
        float g2 = ld ? bf2f(h2b[(size_t)s2 * 10 + l]) : 0.f;
        float g3 = ld ? bf2f(h2b[(size_t)s3 * 10 + l]) : 0.f;
        UPD1(m0, d0, a0, e0, g0);
        UPD1(m1, d1, a1, e1, g1);
        UPD1(m2, d2, a2, e2, g2);
        UPD1(m3, d3, a3, e3, g3);
    }
    for (; i < cw; ++i) {
        int s = sp[i];
        float ev = LRELU(bf2f(asrc2b[s]) + adn);
        float gv = ld ? bf2f(h2b[(size_t)s * 10 + l]) : 0.f;
        UPD1(m0, d0, a0, ev, gv);
    }
    float mM = fmaxf(fmaxf(m0, m1), fmaxf(m2, m3));
    float w0 = fexp2(m0 - mM), w1 = fexp2(m1 - mM);
    float w2 = fexp2(m2 - mM), w3 = fexp2(m3 - mM);
    float den = d0 * w0 + d1 * w1 + d2 * w2 + d3 * w3;
    float acc = a0 * w0 + a1 * w1 + a2 * w2 + a3 * w3;
    if (ld) agg2[(size_t)wid * 10 + l] = acc / (den + 1e-16f);
}

// ---------------- pool (+bias) + log_softmax; block per graph ----------------
__global__ void k_pool_final(const float* __restrict__ agg2, const float* __restrict__ b2,
                             const int* __restrict__ batch, float* __restrict__ out,
                             int N, int G) {
    int g = blockIdx.x;
    int lo = 0, hi = N;
    while (lo < hi) { int mid = (lo + hi) >> 1; if (batch[mid] < g) lo = mid + 1; else hi = mid; }
    int s = lo;
    lo = s; hi = N;
    while (lo < hi) { int mid = (lo + hi) >> 1; if (batch[mid] < g + 1) lo = mid + 1; else hi = mid; }
    int e = lo;
    int tid = threadIdx.x;
    float acc[10];
#pragma unroll
    for (int j = 0; j < 10; ++j) acc[j] = 0.f;
    for (int n = s + tid; n < e; n += 256) {
        const float* r = agg2 + (size_t)n * 10;
#pragma unroll
        for (int j = 0; j < 10; ++j) acc[j] += r[j];
    }
    __shared__ float red[256 * 10];
#pragma unroll
    for (int j = 0; j < 10; ++j) red[tid * 10 + j] = acc[j];
    __syncthreads();
    for (int st = 128; st > 0; st >>= 1) {
        if (tid < st)
#pragma unroll
            for (int j = 0; j < 10; ++j) red[tid * 10 + j] += red[(tid + st) * 10 + j];
        __syncthreads();
    }
    if (tid == 0) {
        int c = e - s;
        float v[10], m = -1e30f;
#pragma unroll
        for (int j = 0; j < 10; ++j) {
            v[j] = (c > 0) ? red[j] / (float)c + b2[j] : 0.f;
            m = fmaxf(m, v[j]);
        }
        float ssum = 0.f;
#pragma unroll
        for (int j = 0; j < 10; ++j) ssum += expf(v[j] - m);
        float ls = logf(ssum);
#pragma unroll
        for (int j = 0; j < 10; ++j) out[(size_t)g * 10 + j] = v[j] - m - ls;
    }
}

extern "C" void kernel_launch(void* const* d_in, const int* in_sizes, int n_in,
                              void* d_out, int out_size, void* d_ws, size_t ws_size,
                              hipStream_t stream) {
    const float* x     = (const float*)d_in[0];
    const int*   ei    = (const int*)d_in[1];
    const int*   batch = (const int*)d_in[2];
    const float* W1    = (const float*)d_in[3];
    const float* as1w  = (const float*)d_in[4];
    const float* ad1w  = (const float*)d_in[5];
    const float* b1    = (const float*)d_in[6];
    const float* W2    = (const float*)d_in[7];
    const float* as2w  = (const float*)d_in[8];
    const float* ad2w  = (const float*)d_in[9];
    const float* b2    = (const float*)d_in[10];

    const int N  = in_sizes[0] / 128;
    const int E  = in_sizes[1] / 2;
    const int G  = out_size / 10;
    const int* srcE = ei;
    const int* dstE = ei + E;

    auto cdiv = [](long long a, long long b) { return (int)((a + b - 1) / b); };
    const int NB = cdiv(E, CH);

    // ---- workspace layout ----
    size_t Nz = (size_t)N;
    unsigned short* h1b = (unsigned short*)d_ws;        // N*64 bf16
    float* agg2  = (float*)d_ws;                        // ALIAS: h1b dead after gather1
    unsigned short* asrc1b = h1b + Nz * 64;             // N*8 bf16
    float* adst1 = (float*)(asrc1b + Nz * 8);           // N*8 f32
    unsigned short* h2b = (unsigned short*)(adst1 + Nz * 8); // N*10 bf16
    unsigned short* asrc2b = h2b + Nz * 10;             // N bf16
    float* adst2 = (float*)(asrc2b + Nz + (Nz & 1));    // N f32 (align 4B)
    float* agg1  = adst2 + Nz;                          // N*64 f32
    int2*  pairs = (int2*)agg1;                         // ALIAS: dead before gather1 writes agg1
    int* cntA    = (int*)(agg1 + Nz * 64);              // N
    int* exclA   = cntA + Nz;                           // N
    int* srcsA   = exclA + Nz;                          // E
    int* bhA     = srcsA + E;                           // 512*NB
    int* pstartA = bhA + (size_t)512 * NB;              // 512*NB
    int* totalA  = pstartA + (size_t)512 * NB;          // 512
    int* boffA   = totalA + 512;                        // 512

    const int B = 256;

    // layer-1 GEMM (+alpha dots): x-in-LDS transposed, scalar W
    k_gemm1<<<cdiv(N, 64), B, 0, stream>>>(x, W1, as1w, ad1w, h1b, asrc1b, adst1, N);

    // graph-bucket CSR build (no global atomics)
    k_bhist<<<NB, B, 0, stream>>>(dstE, batch, E, NB, G, bhA);
    k_mscan<<<512, 512, 0, stream>>>(bhA, NB, pstartA, totalA);
    k_scan_top<<<1, 1024, 0, stream>>>(totalA, G, boffA);
    k_bscatter<<<NB, B, 0, stream>>>(srcE, dstE, batch, boffA, pstartA, E, NB, G, pairs);
    k_csr_local<<<G, 512, 0, stream>>>(pairs, boffA, batch, E, N, G, cntA, exclA, srcsA);

    // layer 1 gather: 16 nodes/block (4/wave), 4ch/lane
    k_gather1<<<cdiv(N, 16), B, 0, stream>>>(srcsA, exclA, cntA, asrc1b, adst1, h1b, agg1, N);
    k_fin1<<<cdiv(N, B), B, 0, stream>>>(agg1, b1, W2, as2w, ad2w, h2b, asrc2b, adst2, N);

    // layer 2 gather (agg2 aliases dead h1b)
    k_gather2<<<cdiv(N, 16), B, 0, stream>>>(srcsA, exclA, cntA, asrc2b, adst2, h2b, agg2, N);

    // pool + log_softmax
    k_pool_final<<<G, B, 0, stream>>>(agg2, b2, batch, (float*)d_out, N, G);
}

// Round 11
// 224.371 us; speedup vs baseline: 1.0037x; 1.0037x over previous
//
#include <hip/hip_runtime.h>
#include <math.h>

#define L2E 1.44269504088896f
#define LRELU(v) fmaxf((v), 0.2f * (v))

__device__ __forceinline__ float fexp2(float v) { return __builtin_amdgcn_exp2f(v); }

// bf16 helpers (RNE pack, exact unpack)
__device__ __forceinline__ unsigned short f2bf(float f) {
    unsigned u = __float_as_uint(f);
    u += 0x7FFFu + ((u >> 16) & 1u);
    return (unsigned short)(u >> 16);
}
__device__ __forceinline__ float bf2f(unsigned short b) {
    return __uint_as_float((unsigned)b << 16);
}

// base-2 online-softmax update, 4 channels (float4 acc)
#define UPD4(mm, dd, AA, ev, GG)           \
    {                                      \
        float mn_ = fmaxf(mm, ev);         \
        float sc_ = fexp2(mm - mn_);       \
        float w_  = fexp2(ev - mn_);       \
        dd = dd * sc_ + w_;                \
        AA.x = AA.x * sc_ + w_ * (GG).x;   \
        AA.y = AA.y * sc_ + w_ * (GG).y;   \
        AA.z = AA.z * sc_ + w_ * (GG).z;   \
        AA.w = AA.w * sc_ + w_ * (GG).w;   \
        mm = mn_;                          \
    }
#define UPD1(mm, dd, aa, ev, hv)           \
    {                                      \
        float mn_ = fmaxf(mm, ev);         \
        float sc_ = fexp2(mm - mn_);       \
        float w_  = fexp2(ev - mn_);       \
        dd = dd * sc_ + w_;                \
        aa = aa * sc_ + w_ * (hv);         \
        mm = mn_;                          \
    }

#define CH 4096   // edges per bucket-build block

__device__ __forceinline__ float4 b4f(ushort4 u) {
    float4 r;
    r.x = bf2f(u.x); r.y = bf2f(u.y); r.z = bf2f(u.z); r.w = bf2f(u.w);
    return r;
}

// ---------------- layer-1 GEMM: W in LDS, 8 nodes/thread, x double-buffered ----------------
// Block = 256 threads; thread (g,h): 8 nodes x 8 cols (head h). 256 nodes/block.
// Per kk: 8 ds_read_b128 (96 cy) vs 256 FMA (512 cy) per wave -> VALU-bound;
// xA/xB ping-pong hides global x latency inside the single resident wave/SIMD.
__global__ __launch_bounds__(256) void k_gemm1(
        const float* __restrict__ x, const float* __restrict__ W,
        const float* __restrict__ a_src, const float* __restrict__ a_dst,
        unsigned short* __restrict__ h1b, unsigned short* __restrict__ asrcb,
        float* __restrict__ adst, int N) {
    __shared__ float Wl[128 * 64];
    int tid = threadIdx.x;
    {
        const float4* W4 = (const float4*)W;
        float4* Wl4 = (float4*)Wl;
#pragma unroll
        for (int i = 0; i < 8; ++i) Wl4[tid + 256 * i] = W4[tid + 256 * i];
    }
    __syncthreads();

    int g = tid >> 3, h = tid & 7;
    int n0 = blockIdx.x * 256 + g * 8;
    const float4* x4 = (const float4*)x;
    const float4 z4 = {0.f, 0.f, 0.f, 0.f};

    const float4* xp[8];
    bool vn[8];
#pragma unroll
    for (int nn = 0; nn < 8; ++nn) {
        vn[nn] = (n0 + nn) < N;
        xp[nn] = x4 + (size_t)(n0 + nn) * 32;
    }

    float acc[8][8];
#pragma unroll
    for (int nn = 0; nn < 8; ++nn)
#pragma unroll
        for (int c = 0; c < 8; ++c) acc[nn][c] = 0.f;

    float4 xA[8], xB[8];
#pragma unroll
    for (int nn = 0; nn < 8; ++nn) xA[nn] = vn[nn] ? xp[nn][0] : z4;

#define GEMM_STEP(XBUF, KK)                                              \
    {                                                                    \
        _Pragma("unroll")                                                \
        for (int j = 0; j < 4; ++j) {                                    \
            const float* wr = &Wl[((KK) * 4 + j) * 64 + h * 8];          \
            float wv[8];                                                 \
            _Pragma("unroll")                                            \
            for (int c = 0; c < 8; ++c) wv[c] = wr[c];                   \
            _Pragma("unroll")                                            \
            for (int nn = 0; nn < 8; ++nn) {                             \
                float xv = ((const float*)&XBUF[nn])[j];                 \
                _Pragma("unroll")                                        \
                for (int c = 0; c < 8; ++c)                              \
                    acc[nn][c] = fmaf(xv, wv[c], acc[nn][c]);            \
            }                                                            \
        }                                                                \
    }

    for (int kk = 0; kk < 32; kk += 2) {
        // prefetch kk+1 into xB, then compute kk from xA
#pragma unroll
        for (int nn = 0; nn < 8; ++nn) xB[nn] = vn[nn] ? xp[nn][kk + 1] : z4;
        GEMM_STEP(xA, kk)
        // prefetch kk+2 into xA, then compute kk+1 from xB
        if (kk + 2 < 32) {
#pragma unroll
            for (int nn = 0; nn < 8; ++nn) xA[nn] = vn[nn] ? xp[nn][kk + 2] : z4;
        }
        GEMM_STEP(xB, kk + 1)
    }
#undef GEMM_STEP

    const float* as = a_src + h * 8;
    const float* ad = a_dst + h * 8;
#pragma unroll
    for (int nn = 0; nn < 8; ++nn) {
        int n = n0 + nn;
        if (n >= N) break;
        float s = 0.f, d = 0.f;
        uint4 pk;
        unsigned* pw = (unsigned*)&pk;
#pragma unroll
        for (int c = 0; c < 8; c += 2) {
            s = fmaf(acc[nn][c], as[c], s);     d = fmaf(acc[nn][c], ad[c], d);
            s = fmaf(acc[nn][c+1], as[c+1], s); d = fmaf(acc[nn][c+1], ad[c+1], d);
            pw[c >> 1] = (unsigned)f2bf(acc[nn][c]) | ((unsigned)f2bf(acc[nn][c+1]) << 16);
        }
        *(uint4*)&h1b[(size_t)n * 64 + h * 8] = pk;
        asrcb[n * 8 + h] = f2bf(s * L2E);
        adst[n * 8 + h] = d * L2E;
    }
}

// ---------------- graph-bucket sort (zero global atomics) ----------------

__global__ __launch_bounds__(256) void k_bhist(const int* __restrict__ dstE,
                                               const int* __restrict__ batch,
                                               int E, int NB, int G, int* __restrict__ bh) {
    __shared__ int lh[512];
    int tid = threadIdx.x, b = blockIdx.x;
    lh[tid] = 0; lh[tid + 256] = 0;
    __syncthreads();
#pragma unroll
    for (int i = 0; i < CH / 256; ++i) {
        int e = b * CH + i * 256 + tid;
        if (e < E) atomicAdd(&lh[batch[dstE[e]]], 1);
    }
    __syncthreads();
    if (tid < G)       bh[(size_t)tid * NB + b] = lh[tid];
    if (tid + 256 < G) bh[(size_t)(tid + 256) * NB + b] = lh[tid + 256];
}

__global__ __launch_bounds__(512) void k_mscan(const int* __restrict__ bh, int NB,
                                               int* __restrict__ pstart, int* __restrict__ total) {
    __shared__ int buf[512];
    int bin = blockIdx.x, t = threadIdx.x;
    int v = (t < NB) ? bh[(size_t)bin * NB + t] : 0;
    buf[t] = v;
    __syncthreads();
    for (int off = 1; off < 512; off <<= 1) {
        int u = (t >= off) ? buf[t - off] : 0;
        __syncthreads();
        buf[t] += u;
        __syncthreads();
    }
    if (t < NB) pstart[(size_t)bin * NB + t] = buf[t] - v;
    if (t == 511) total[bin] = buf[511];
}

__global__ __launch_bounds__(1024) void k_scan_top(const int* __restrict__ total, int nb,
                                                   int* __restrict__ boff) {
    __shared__ int buf[1024];
    int t = threadIdx.x;
    int v = (t < nb) ? total[t] : 0;
    buf[t] = v;
    __syncthreads();
    for (int off = 1; off < 1024; off <<= 1) {
        int u = (t >= off) ? buf[t - off] : 0;
        __syncthreads();
        buf[t] += u;
        __syncthreads();
    }
    if (t < nb) boff[t] = buf[t] - v;
}

__global__ __launch_bounds__(256) void k_bscatter(const int* __restrict__ srcE,
                                                  const int* __restrict__ dstE,
                                                  const int* __restrict__ batch,
                                                  const int* __restrict__ boff,
                                                  const int* __restrict__ pstart,
                                                  int E, int NB, int G, int2* __restrict__ pairs) {
    __shared__ int lstart[512];
    __shared__ int lc[512];
    int tid = threadIdx.x, b = blockIdx.x;
#pragma unroll
    for (int j = tid; j < 512; j += 256) {
        lstart[j] = (j < G) ? boff[j] + pstart[(size_t)j * NB + b] : 0;
        lc[j] = 0;
    }
    __syncthreads();
#pragma unroll
    for (int i = 0; i < CH / 256; ++i) {
        int e = b * CH + i * 256 + tid;
        if (e < E) {
            int s = srcE[e], d = dstE[e];
            int bin = batch[d];
            int old = atomicAdd(&lc[bin], 1);
            pairs[lstart[bin] + old] = make_int2(s, d);
        }
    }
}

__global__ __launch_bounds__(512) void k_csr_local(const int2* __restrict__ pairs,
                                                   const int* __restrict__ boff,
                                                   const int* __restrict__ batch,
                                                   int E, int N, int G,
                                                   int* __restrict__ cnt, int* __restrict__ excl,
                                                   int* __restrict__ srcs) {
    __shared__ int lcnt[512];
    __shared__ int buf[512];
    __shared__ int lcur[512];
    int g = blockIdx.x, t = threadIdx.x;
    int lo = 0, hi = N;
    while (lo < hi) { int mid = (lo + hi) >> 1; if (batch[mid] < g) lo = mid + 1; else hi = mid; }
    int ns = lo;
    hi = N;
    while (lo < hi) { int mid = (lo + hi) >> 1; if (batch[mid] < g + 1) lo = mid + 1; else hi = mid; }
    int ne = lo;
    int lnodes = ne - ns;
    int es = boff[g];
    int ee = (g + 1 < G) ? boff[g + 1] : E;

    lcnt[t] = 0;
    __syncthreads();
    for (int e = es + t; e < ee; e += 512) atomicAdd(&lcnt[pairs[e].y - ns], 1);
    __syncthreads();
    int v = lcnt[t];
    buf[t] = v;
    __syncthreads();
    for (int off = 1; off < 512; off <<= 1) {
        int u = (t >= off) ? buf[t - off] : 0;
        __syncthreads();
        buf[t] += u;
        __syncthreads();
    }
    int lex = buf[t] - v;
    lcur[t] = lex;
    if (t < lnodes) {
        cnt[ns + t] = v;
        excl[ns + t] = es + lex;
    }
    __syncthreads();
    for (int e = es + t; e < ee; e += 512) {
        int2 p = pairs[e];
        int pos = atomicAdd(&lcur[p.y - ns], 1);
        srcs[es + pos] = p.x;
    }
}

// ---------------- layer 1 gather: 4 nodes/wave, 16 lanes/node, bf16x4/lane ----------------
__global__ void k_gather1(const int* __restrict__ srcs, const int* __restrict__ excl,
                          const int* __restrict__ cnt,
                          const unsigned short* __restrict__ asrcb, const float* __restrict__ adst1,
                          const unsigned short* __restrict__ h1b, float* __restrict__ agg, int N) {
    int tid = blockIdx.x * 256 + threadIdx.x;
    int wave = tid >> 6;
    int lane = threadIdx.x & 63;
    int q = lane >> 4;            // node slot
    int l = lane & 15;
    int wid = wave * 4 + q;
    if (wid >= N) return;
    int h = l >> 1;               // head (2 lanes/head)
    int c0 = l * 4;               // channels c0..c0+3

    int beg = excl[wid];
    int cw  = cnt[wid];
    const int* sp = srcs + beg;
    float adh = adst1[wid * 8 + h];

    // self-loop init on chain 0
    float4 A0 = b4f(*(const ushort4*)&h1b[(size_t)wid * 64 + c0]);
    float m0 = LRELU(bf2f(asrcb[wid * 8 + h]) + adh), d0 = 1.f;
    float4 A1 = {0.f, 0.f, 0.f, 0.f}, A2 = A1, A3 = A1;
    float m1 = -INFINITY, d1 = 0.f;
    float m2 = -INFINITY, d2 = 0.f;
    float m3 = -INFINITY, d3 = 0.f;

    int i = 0;
    for (; i + 4 <= cw; i += 4) {
        int s0 = sp[i], s1 = sp[i + 1], s2 = sp[i + 2], s3 = sp[i + 3];
        float e0 = LRELU(bf2f(asrcb[s0 * 8 + h]) + adh);
        float e1 = LRELU(bf2f(asrcb[s1 * 8 + h]) + adh);
        float e2 = LRELU(bf2f(asrcb[s2 * 8 + h]) + adh);
        float e3 = LRELU(bf2f(asrcb[s3 * 8 + h]) + adh);
        float4 g0 = b4f(*(const ushort4*)&h1b[(size_t)s0 * 64 + c0]);
        float4 g1 = b4f(*(const ushort4*)&h1b[(size_t)s1 * 64 + c0]);
        float4 g2 = b4f(*(const ushort4*)&h1b[(size_t)s2 * 64 + c0]);
        float4 g3 = b4f(*(const ushort4*)&h1b[(size_t)s3 * 64 + c0]);
        UPD4(m0, d0, A0, e0, g0);
        UPD4(m1, d1, A1, e1, g1);
        UPD4(m2, d2, A2, e2, g2);
        UPD4(m3, d3, A3, e3, g3);
    }
    for (; i < cw; ++i) {
        int s = sp[i];
        float ev = LRELU(bf2f(asrcb[s * 8 + h]) + adh);
        float4 gv = b4f(*(const ushort4*)&h1b[(size_t)s * 64 + c0]);
        UPD4(m0, d0, A0, ev, gv);
    }
    float mM = fmaxf(fmaxf(m0, m1), fmaxf(m2, m3));
    float w0 = fexp2(m0 - mM), w1 = fexp2(m1 - mM);
    float w2 = fexp2(m2 - mM), w3 = fexp2(m3 - mM);
    float den = d0 * w0 + d1 * w1 + d2 * w2 + d3 * w3;
    float inv = 1.f / (den + 1e-16f);
    float4 r;
    r.x = (A0.x * w0 + A1.x * w1 + A2.x * w2 + A3.x * w3) * inv;
    r.y = (A0.y * w0 + A1.y * w1 + A2.y * w2 + A3.y * w3) * inv;
    r.z = (A0.z * w0 + A1.z * w1 + A2.z * w2 + A3.z * w3) * inv;
    r.w = (A0.w * w0 + A1.w * w1 + A2.w * w2 + A3.w * w3) * inv;
    *(float4*)&agg[(size_t)wid * 64 + c0] = r;
}

// out1 = elu(agg + b1); h2 = out1 @ W2 (64x10) -> bf16; layer-2 alpha dots (x log2e)
__global__ void k_fin1(const float* __restrict__ agg, const float* __restrict__ b1,
                       const float* __restrict__ W2,
                       const float* __restrict__ a_src2, const float* __restrict__ a_dst2,
                       unsigned short* __restrict__ h2b, unsigned short* __restrict__ asrc2b,
                       float* __restrict__ adst2, int N) {
    int n = blockIdx.x * 256 + threadIdx.x;
    if (n >= N) return;
    float acc[10];
#pragma unroll
    for (int j = 0; j < 10; ++j) acc[j] = 0.f;
    const float* ar = agg + (size_t)n * 64;
#pragma unroll 8
    for (int k = 0; k < 64; ++k) {
        float r = ar[k] + b1[k];
        r = r > 0.f ? r : expm1f(r);   // elu
#pragma unroll
        for (int j = 0; j < 10; ++j) acc[j] = fmaf(r, W2[k * 10 + j], acc[j]);
    }
    float s = 0.f, d = 0.f;
    unsigned pw[5];
#pragma unroll
    for (int j = 0; j < 10; j += 2) {
        s = fmaf(acc[j], a_src2[j], s);     d = fmaf(acc[j], a_dst2[j], d);
        s = fmaf(acc[j+1], a_src2[j+1], s); d = fmaf(acc[j+1], a_dst2[j+1], d);
        pw[j >> 1] = (unsigned)f2bf(acc[j]) | ((unsigned)f2bf(acc[j+1]) << 16);
    }
    unsigned* hw = (unsigned*)&h2b[(size_t)n * 10];
#pragma unroll
    for (int j = 0; j < 5; ++j) hw[j] = pw[j];
    asrc2b[n] = f2bf(s * L2E);
    adst2[n] = d * L2E;
}

// ---------------- layer 2 gather: 4 nodes/wave, 16 lanes/node ----------------
__global__ void k_gather2(const int* __restrict__ srcs, const int* __restrict__ excl,
                          const int* __restrict__ cnt,
                          const unsigned short* __restrict__ asrc2b, const float* __restrict__ adst2,
                          const unsigned short* __restrict__ h2b, float* __restrict__ agg2, int N) {
    int tid = blockIdx.x * 256 + threadIdx.x;
    int wave = tid >> 6;
    int lane = threadIdx.x & 63;
    int q = lane >> 4;
    int l = lane & 15;
    int wid = wave * 4 + q;
    if (wid >= N) return;

    int beg = excl[wid];
    int cw  = cnt[wid];
    const int* sp = srcs + beg;
    float adn = adst2[wid];
    bool ld = l < 10;

    float m0 = LRELU(bf2f(asrc2b[wid]) + adn), d0 = 1.f;
    float a0 = ld ? bf2f(h2b[(size_t)wid * 10 + l]) : 0.f;
    float m1 = -INFINITY, d1 = 0.f, a1 = 0.f;
    float m2 = -INFINITY, d2 = 0.f, a2 = 0.f;
    float m3 = -INFINITY, d3 = 0.f, a3 = 0.f;

    int i = 0;
    for (; i + 4 <= cw; i += 4) {
        int s0 = sp[i], s1 = sp[i + 1], s2 = sp[i + 2], s3 = sp[i + 3];
        float e0 = LRELU(bf2f(asrc2b[s0]) + adn);
        float e1 = LRELU(bf2f(asrc2b[s1]) + adn);
        float e2 = LRELU(bf2f(asrc2b[s2]) + adn);
        float e3 = LRELU(bf2f(asrc2b[s3]) + adn);
        float g0 = ld ? bf2f(h2b[(size_t)s0 * 10 + l]) : 0.f;
        float g1 = ld ? bf2f(h2b[(size_t)s1 * 10 + l]) : 0.f;
        float g2 = ld ? bf2f(h2b[(size_t)s2 * 10 + l]) : 0.f;
        float g3 = ld ? bf2f(h2b[(size_t)s3 * 10 + l]) : 0.f;
        UPD1(m0, d0, a0, e0, g0);
        UPD1(m1, d1, a1, e1, g1);
        UPD1(m2, d2, a2, e2, g2);
        UPD1(m3, d3, a3, e3, g3);
    }
    for (; i < cw; ++i) {
        int s = sp[i];
        float ev = LRELU(bf2f(asrc2b[s]) + adn);
        float gv = ld ? bf2f(h2b[(size_t)s * 10 + l]) : 0.f;
        UPD1(m0, d0, a0, ev, gv);
    }
    float mM = fmaxf(fmaxf(m0, m1), fmaxf(m2, m3));
    float w0 = fexp2(m0 - mM), w1 = fexp2(m1 - mM);
    float w2 = fexp2(m2 - mM), w3 = fexp2(m3 - mM);
    float den = d0 * w0 + d1 * w1 + d2 * w2 + d3 * w3;
    float acc = a0 * w0 + a1 * w1 + a2 * w2 + a3 * w3;
    if (ld) agg2[(size_t)wid * 10 + l] = acc / (den + 1e-16f);
}

// ---------------- pool (+bias) + log_softmax; block per graph ----------------
__global__ void k_pool_final(const float* __restrict__ agg2, const float* __restrict__ b2,
                             const int* __restrict__ batch, float* __restrict__ out,
                             int N, int G) {
    int g = blockIdx.x;
    int lo = 0, hi = N;
    while (lo < hi) { int mid = (lo + hi) >> 1; if (batch[mid] < g) lo = mid + 1; else hi = mid; }
    int s = lo;
    lo = s; hi = N;
    while (lo < hi) { int mid = (lo + hi) >> 1; if (batch[mid] < g + 1) lo = mid + 1; else hi = mid; }
    int e = lo;
    int tid = threadIdx.x;
    float acc[10];
#pragma unroll
    for (int j = 0; j < 10; ++j) acc[j] = 0.f;
    for (int n = s + tid; n < e; n += 256) {
        const float* r = agg2 + (size_t)n * 10;
#pragma unroll
        for (int j = 0; j < 10; ++j) acc[j] += r[j];
    }
    __shared__ float red[256 * 10];
#pragma unroll
    for (int j = 0; j < 10; ++j) red[tid * 10 + j] = acc[j];
    __syncthreads();
    for (int st = 128; st > 0; st >>= 1) {
        if (tid < st)
#pragma unroll
            for (int j = 0; j < 10; ++j) red[tid * 10 + j] += red[(tid + st) * 10 + j];
        __syncthreads();
    }
    if (tid == 0) {
        int c = e - s;
        float v[10], m = -1e30f;
#pragma unroll
        for (int j = 0; j < 10; ++j) {
            v[j] = (c > 0) ? red[j] / (float)c + b2[j] : 0.f;
            m = fmaxf(m, v[j]);
        }
        float ssum = 0.f;
#pragma unroll
        for (int j = 0; j < 10; ++j) ssum += expf(v[j] - m);
        float ls = logf(ssum);
#pragma unroll
        for (int j = 0; j < 10; ++j) out[(size_t)g * 10 + j] = v[j] - m - ls;
    }
}

extern "C" void kernel_launch(void* const* d_in, const int* in_sizes, int n_in,
                              void* d_out, int out_size, void* d_ws, size_t ws_size,
                              hipStream_t stream) {
    const float* x     = (const float*)d_in[0];
    const int*   ei    = (const int*)d_in[1];
    const int*   batch = (const int*)d_in[2];
    const float* W1    = (const float*)d_in[3];
    const float* as1w  = (const float*)d_in[4];
    const float* ad1w  = (const float*)d_in[5];
    const float* b1    = (const float*)d_in[6];
    const float* W2    = (const float*)d_in[7];
    const float* as2w  = (const float*)d_in[8];
    const float* ad2w  = (const float*)d_in[9];
    const float* b2    = (const float*)d_in[10];

    const int N  = in_sizes[0] / 128;
    const int E  = in_sizes[1] / 2;
    const int G  = out_size / 10;
    const int* srcE = ei;
    const int* dstE = ei + E;

    auto cdiv = [](long long a, long long b) { return (int)((a + b - 1) / b); };
    const int NB = cdiv(E, CH);

    // ---- workspace layout ----
    size_t Nz = (size_t)N;
    unsigned short* h1b = (unsigned short*)d_ws;        // N*64 bf16
    float* agg2  = (float*)d_ws;                        // ALIAS: h1b dead after gather1
    unsigned short* asrc1b = h1b + Nz * 64;             // N*8 bf16
    float* adst1 = (float*)(asrc1b + Nz * 8);           // N*8 f32
    unsigned short* h2b = (unsigned short*)(adst1 + Nz * 8); // N*10 bf16
    unsigned short* asrc2b = h2b + Nz * 10;             // N bf16
    float* adst2 = (float*)(asrc2b + Nz + (Nz & 1));    // N f32 (align 4B)
    float* agg1  = adst2 + Nz;                          // N*64 f32
    int2*  pairs = (int2*)agg1;                         // ALIAS: dead before gather1 writes agg1
    int* cntA    = (int*)(agg1 + Nz * 64);              // N
    int* exclA   = cntA + Nz;                           // N
    int* srcsA   = exclA + Nz;                          // E
    int* bhA     = srcsA + E;                           // 512*NB
    int* pstartA = bhA + (size_t)512 * NB;              // 512*NB
    int* totalA  = pstartA + (size_t)512 * NB;          // 512
    int* boffA   = totalA + 512;                        // 512

    const int B = 256;

    // layer-1 GEMM (+alpha dots): W-in-LDS, 8 nodes/thread, x prefetch
    k_gemm1<<<cdiv(N, 256), B, 0, stream>>>(x, W1, as1w, ad1w, h1b, asrc1b, adst1, N);

    // graph-bucket CSR build (no global atomics)
    k_bhist<<<NB, B, 0, stream>>>(dstE, batch, E, NB, G, bhA);
    k_mscan<<<512, 512, 0, stream>>>(bhA, NB, pstartA, totalA);
    k_scan_top<<<1, 1024, 0, stream>>>(totalA, G, boffA);
    k_bscatter<<<NB, B, 0, stream>>>(srcE, dstE, batch, boffA, pstartA, E, NB, G, pairs);
    k_csr_local<<<G, 512, 0, stream>>>(pairs, boffA, batch, E, N, G, cntA, exclA, srcsA);

    // layer 1 gather: 16 nodes/block (4/wave), 4ch/lane
    k_gather1<<<cdiv(N, 16), B, 0, stream>>>(srcsA, exclA, cntA, asrc1b, adst1, h1b, agg1, N);
    k_fin1<<<cdiv(N, B), B, 0, stream>>>(agg1, b1, W2, as2w, ad2w, h2b, asrc2b, adst2, N);

    // layer 2 gather (agg2 aliases dead h1b)
    k_gather2<<<cdiv(N, 16), B, 0, stream>>>(srcsA, exclA, cntA, asrc2b, adst2, h2b, agg2, N);

    // pool + log_softmax
    k_pool_final<<<G, B, 0, stream>>>(agg2, b2, batch, (float*)d_out, N, G);
}

// Round 12
// 213.953 us; speedup vs baseline: 1.0525x; 1.0487x over previous
//
#include <hip/hip_runtime.h>
#include <math.h>

#define L2E 1.44269504088896f
#define LRELU(v) fmaxf((v), 0.2f * (v))

__device__ __forceinline__ float fexp2(float v) { return __builtin_amdgcn_exp2f(v); }

// bf16 helpers (RNE pack, exact unpack)
__device__ __forceinline__ unsigned short f2bf(float f) {
    unsigned u = __float_as_uint(f);
    u += 0x7FFFu + ((u >> 16) & 1u);
    return (unsigned short)(u >> 16);
}
__device__ __forceinline__ float bf2f(unsigned short b) {
    return __uint_as_float((unsigned)b << 16);
}

// base-2 online-softmax update, 4 channels (float4 acc)
#define UPD4(mm, dd, AA, ev, GG)           \
    {                                      \
        float mn_ = fmaxf(mm, ev);         \
        float sc_ = fexp2(mm - mn_);       \
        float w_  = fexp2(ev - mn_);       \
        dd = dd * sc_ + w_;                \
        AA.x = AA.x * sc_ + w_ * (GG).x;   \
        AA.y = AA.y * sc_ + w_ * (GG).y;   \
        AA.z = AA.z * sc_ + w_ * (GG).z;   \
        AA.w = AA.w * sc_ + w_ * (GG).w;   \
        mm = mn_;                          \
    }
#define UPD1(mm, dd, aa, ev, hv)           \
    {                                      \
        float mn_ = fmaxf(mm, ev);         \
        float sc_ = fexp2(mm - mn_);       \
        float w_  = fexp2(ev - mn_);       \
        dd = dd * sc_ + w_;                \
        aa = aa * sc_ + w_ * (hv);         \
        mm = mn_;                          \
    }

#define CH 4096   // edges per bucket-build block

__device__ __forceinline__ float4 b4f(ushort4 u) {
    float4 r;
    r.x = bf2f(u.x); r.y = bf2f(u.y); r.z = bf2f(u.z); r.w = bf2f(u.w);
    return r;
}

// ---------------- layer-1 GEMM: W in LDS, 4 nodes/thread, 128 nodes/block ----------------
// Per kk per wave: 8 ds_read_b128 (~96cy) vs 128 FMA (~256cy). Grid = N/128 ~ 782
// blocks -> 3 blocks/CU -> 3 waves/SIMD hide global x latency via TLP.
__global__ __launch_bounds__(256) void k_gemm1(
        const float* __restrict__ x, const float* __restrict__ W,
        const float* __restrict__ a_src, const float* __restrict__ a_dst,
        unsigned short* __restrict__ h1b, unsigned short* __restrict__ asrcb,
        float* __restrict__ adst, int N) {
    __shared__ float Wl[128 * 64];
    int tid = threadIdx.x;
    {
        const float4* W4 = (const float4*)W;
        float4* Wl4 = (float4*)Wl;
#pragma unroll
        for (int i = 0; i < 8; ++i) Wl4[tid + 256 * i] = W4[tid + 256 * i];
    }
    __syncthreads();

    int g = tid >> 3, h = tid & 7;
    int n0 = blockIdx.x * 128 + g * 4;     // 32 g-slots x 4 nodes = 128 nodes/block
    const float4* x4 = (const float4*)x;
    const float4 z4 = {0.f, 0.f, 0.f, 0.f};

    bool vn[4];
#pragma unroll
    for (int nn = 0; nn < 4; ++nn) vn[nn] = (n0 + nn) < N;

    float acc[4][8];
#pragma unroll
    for (int nn = 0; nn < 4; ++nn)
#pragma unroll
        for (int c = 0; c < 8; ++c) acc[nn][c] = 0.f;

    for (int kk = 0; kk < 32; ++kk) {
        float4 xa[4];
#pragma unroll
        for (int nn = 0; nn < 4; ++nn)
            xa[nn] = vn[nn] ? x4[(size_t)(n0 + nn) * 32 + kk] : z4;
#pragma unroll
        for (int j = 0; j < 4; ++j) {
            const float* wr = &Wl[(kk * 4 + j) * 64 + h * 8];
            float wv[8];
#pragma unroll
            for (int c = 0; c < 8; ++c) wv[c] = wr[c];
#pragma unroll
            for (int nn = 0; nn < 4; ++nn) {
                float xv = ((const float*)&xa[nn])[j];
#pragma unroll
                for (int c = 0; c < 8; ++c) acc[nn][c] = fmaf(xv, wv[c], acc[nn][c]);
            }
        }
    }

    const float* as = a_src + h * 8;
    const float* ad = a_dst + h * 8;
#pragma unroll
    for (int nn = 0; nn < 4; ++nn) {
        int n = n0 + nn;
        if (n >= N) break;
        float s = 0.f, d = 0.f;
        uint4 pk;
        unsigned* pw = (unsigned*)&pk;
#pragma unroll
        for (int c = 0; c < 8; c += 2) {
            s = fmaf(acc[nn][c], as[c], s);     d = fmaf(acc[nn][c], ad[c], d);
            s = fmaf(acc[nn][c+1], as[c+1], s); d = fmaf(acc[nn][c+1], ad[c+1], d);
            pw[c >> 1] = (unsigned)f2bf(acc[nn][c]) | ((unsigned)f2bf(acc[nn][c+1]) << 16);
        }
        *(uint4*)&h1b[(size_t)n * 64 + h * 8] = pk;
        asrcb[n * 8 + h] = f2bf(s * L2E);
        adst[n * 8 + h] = d * L2E;
    }
}

// ---------------- graph-bucket sort (zero global atomics) ----------------

__global__ __launch_bounds__(256) void k_bhist(const int* __restrict__ dstE,
                                               const int* __restrict__ batch,
                                               int E, int NB, int G, int* __restrict__ bh) {
    __shared__ int lh[512];
    int tid = threadIdx.x, b = blockIdx.x;
    lh[tid] = 0; lh[tid + 256] = 0;
    __syncthreads();
#pragma unroll
    for (int i = 0; i < CH / 256; ++i) {
        int e = b * CH + i * 256 + tid;
        if (e < E) atomicAdd(&lh[batch[dstE[e]]], 1);
    }
    __syncthreads();
    if (tid < G)       bh[(size_t)tid * NB + b] = lh[tid];
    if (tid + 256 < G) bh[(size_t)(tid + 256) * NB + b] = lh[tid + 256];
}

__global__ __launch_bounds__(512) void k_mscan(const int* __restrict__ bh, int NB,
                                               int* __restrict__ pstart, int* __restrict__ total) {
    __shared__ int buf[512];
    int bin = blockIdx.x, t = threadIdx.x;
    int v = (t < NB) ? bh[(size_t)bin * NB + t] : 0;
    buf[t] = v;
    __syncthreads();
    for (int off = 1; off < 512; off <<= 1) {
        int u = (t >= off) ? buf[t - off] : 0;
        __syncthreads();
        buf[t] += u;
        __syncthreads();
    }
    if (t < NB) pstart[(size_t)bin * NB + t] = buf[t] - v;
    if (t == 511) total[bin] = buf[511];
}

__global__ __launch_bounds__(1024) void k_scan_top(const int* __restrict__ total, int nb,
                                                   int* __restrict__ boff) {
    __shared__ int buf[1024];
    int t = threadIdx.x;
    int v = (t < nb) ? total[t] : 0;
    buf[t] = v;
    __syncthreads();
    for (int off = 1; off < 1024; off <<= 1) {
        int u = (t >= off) ? buf[t - off] : 0;
        __syncthreads();
        buf[t] += u;
        __syncthreads();
    }
    if (t < nb) boff[t] = buf[t] - v;
}

__global__ __launch_bounds__(256) void k_bscatter(const int* __restrict__ srcE,
                                                  const int* __restrict__ dstE,
                                                  const int* __restrict__ batch,
                                                  const int* __restrict__ boff,
                                                  const int* __restrict__ pstart,
                                                  int E, int NB, int G, int2* __restrict__ pairs) {
    __shared__ int lstart[512];
    __shared__ int lc[512];
    int tid = threadIdx.x, b = blockIdx.x;
#pragma unroll
    for (int j = tid; j < 512; j += 256) {
        lstart[j] = (j < G) ? boff[j] + pstart[(size_t)j * NB + b] : 0;
        lc[j] = 0;
    }
    __syncthreads();
#pragma unroll
    for (int i = 0; i < CH / 256; ++i) {
        int e = b * CH + i * 256 + tid;
        if (e < E) {
            int s = srcE[e], d = dstE[e];
            int bin = batch[d];
            int old = atomicAdd(&lc[bin], 1);
            pairs[lstart[bin] + old] = make_int2(s, d);
        }
    }
}

__global__ __launch_bounds__(512) void k_csr_local(const int2* __restrict__ pairs,
                                                   const int* __restrict__ boff,
                                                   const int* __restrict__ batch,
                                                   int E, int N, int G,
                                                   int* __restrict__ cnt, int* __restrict__ excl,
                                                   int* __restrict__ srcs) {
    __shared__ int lcnt[512];
    __shared__ int buf[512];
    __shared__ int lcur[512];
    int g = blockIdx.x, t = threadIdx.x;
    int lo = 0, hi = N;
    while (lo < hi) { int mid = (lo + hi) >> 1; if (batch[mid] < g) lo = mid + 1; else hi = mid; }
    int ns = lo;
    hi = N;
    while (lo < hi) { int mid = (lo + hi) >> 1; if (batch[mid] < g + 1) lo = mid + 1; else hi = mid; }
    int ne = lo;
    int lnodes = ne - ns;
    int es = boff[g];
    int ee = (g + 1 < G) ? boff[g + 1] : E;

    lcnt[t] = 0;
    __syncthreads();
    for (int e = es + t; e < ee; e += 512) atomicAdd(&lcnt[pairs[e].y - ns], 1);
    __syncthreads();
    int v = lcnt[t];
    buf[t] = v;
    __syncthreads();
    for (int off = 1; off < 512; off <<= 1) {
        int u = (t >= off) ? buf[t - off] : 0;
        __syncthreads();
        buf[t] += u;
        __syncthreads();
    }
    int lex = buf[t] - v;
    lcur[t] = lex;
    if (t < lnodes) {
        cnt[ns + t] = v;
        excl[ns + t] = es + lex;
    }
    __syncthreads();
    for (int e = es + t; e < ee; e += 512) {
        int2 p = pairs[e];
        int pos = atomicAdd(&lcur[p.y - ns], 1);
        srcs[es + pos] = p.x;
    }
}

// ---------------- layer 1 gather: 4 nodes/wave, 16 lanes/node, bf16x4/lane ----------------
__global__ void k_gather1(const int* __restrict__ srcs, const int* __restrict__ excl,
                          const int* __restrict__ cnt,
                          const unsigned short* __restrict__ asrcb, const float* __restrict__ adst1,
                          const unsigned short* __restrict__ h1b, float* __restrict__ agg, int N) {
    int tid = blockIdx.x * 256 + threadIdx.x;
    int wave = tid >> 6;
    int lane = threadIdx.x & 63;
    int q = lane >> 4;            // node slot
    int l = lane & 15;
    int wid = wave * 4 + q;
    if (wid >= N) return;
    int h = l >> 1;               // head (2 lanes/head)
    int c0 = l * 4;               // channels c0..c0+3

    int beg = excl[wid];
    int cw  = cnt[wid];
    const int* sp = srcs + beg;
    float adh = adst1[wid * 8 + h];

    // self-loop init on chain 0
    float4 A0 = b4f(*(const ushort4*)&h1b[(size_t)wid * 64 + c0]);
    float m0 = LRELU(bf2f(asrcb[wid * 8 + h]) + adh), d0 = 1.f;
    float4 A1 = {0.f, 0.f, 0.f, 0.f}, A2 = A1, A3 = A1;
    float m1 = -INFINITY, d1 = 0.f;
    float m2 = -INFINITY, d2 = 0.f;
    float m3 = -INFINITY, d3 = 0.f;

    int i = 0;
    for (; i + 4 <= cw; i += 4) {
        int s0 = sp[i], s1 = sp[i + 1], s2 = sp[i + 2], s3 = sp[i + 3];
        float e0 = LRELU(bf2f(asrcb[s0 * 8 + h]) + adh);
        float e1 = LRELU(bf2f(asrcb[s1 * 8 + h]) + adh);
        float e2 = LRELU(bf2f(asrcb[s2 * 8 + h]) + adh);
        float e3 = LRELU(bf2f(asrcb[s3 * 8 + h]) + adh);
        float4 g0 = b4f(*(const ushort4*)&h1b[(size_t)s0 * 64 + c0]);
        float4 g1 = b4f(*(const ushort4*)&h1b[(size_t)s1 * 64 + c0]);
        float4 g2 = b4f(*(const ushort4*)&h1b[(size_t)s2 * 64 + c0]);
        float4 g3 = b4f(*(const ushort4*)&h1b[(size_t)s3 * 64 + c0]);
        UPD4(m0, d0, A0, e0, g0);
        UPD4(m1, d1, A1, e1, g1);
        UPD4(m2, d2, A2, e2, g2);
        UPD4(m3, d3, A3, e3, g3);
    }
    for (; i < cw; ++i) {
        int s = sp[i];
        float ev = LRELU(bf2f(asrcb[s * 8 + h]) + adh);
        float4 gv = b4f(*(const ushort4*)&h1b[(size_t)s * 64 + c0]);
        UPD4(m0, d0, A0, ev, gv);
    }
    float mM = fmaxf(fmaxf(m0, m1), fmaxf(m2, m3));
    float w0 = fexp2(m0 - mM), w1 = fexp2(m1 - mM);
    float w2 = fexp2(m2 - mM), w3 = fexp2(m3 - mM);
    float den = d0 * w0 + d1 * w1 + d2 * w2 + d3 * w3;
    float inv = 1.f / (den + 1e-16f);
    float4 r;
    r.x = (A0.x * w0 + A1.x * w1 + A2.x * w2 + A3.x * w3) * inv;
    r.y = (A0.y * w0 + A1.y * w1 + A2.y * w2 + A3.y * w3) * inv;
    r.z = (A0.z * w0 + A1.z * w1 + A2.z * w2 + A3.z * w3) * inv;
    r.w = (A0.w * w0 + A1.w * w1 + A2.w * w2 + A3.w * w3) * inv;
    *(float4*)&agg[(size_t)wid * 64 + c0] = r;
}

// out1 = elu(agg + b1); h2 = out1 @ W2 (64x10) -> bf16; layer-2 alpha dots (x log2e)
__global__ void k_fin1(const float* __restrict__ agg, const float* __restrict__ b1,
                       const float* __restrict__ W2,
                       const float* __restrict__ a_src2, const float* __restrict__ a_dst2,
                       unsigned short* __restrict__ h2b, unsigned short* __restrict__ asrc2b,
                       float* __restrict__ adst2, int N) {
    int n = blockIdx.x * 256 + threadIdx.x;
    if (n >= N) return;
    float acc[10];
#pragma unroll
    for (int j = 0; j < 10; ++j) acc[j] = 0.f;
    const float* ar = agg + (size_t)n * 64;
#pragma unroll 8
    for (int k = 0; k < 64; ++k) {
        float r = ar[k] + b1[k];
        r = r > 0.f ? r : expm1f(r);   // elu
#pragma unroll
        for (int j = 0; j < 10; ++j) acc[j] = fmaf(r, W2[k * 10 + j], acc[j]);
    }
    float s = 0.f, d = 0.f;
    unsigned pw[5];
#pragma unroll
    for (int j = 0; j < 10; j += 2) {
        s = fmaf(acc[j], a_src2[j], s);     d = fmaf(acc[j], a_dst2[j], d);
        s = fmaf(acc[j+1], a_src2[j+1], s); d = fmaf(acc[j+1], a_dst2[j+1], d);
        pw[j >> 1] = (unsigned)f2bf(acc[j]) | ((unsigned)f2bf(acc[j+1]) << 16);
    }
    unsigned* hw = (unsigned*)&h2b[(size_t)n * 10];
#pragma unroll
    for (int j = 0; j < 5; ++j) hw[j] = pw[j];
    asrc2b[n] = f2bf(s * L2E);
    adst2[n] = d * L2E;
}

// ---------------- layer 2 gather: 4 nodes/wave, 16 lanes/node ----------------
__global__ void k_gather2(const int* __restrict__ srcs, const int* __restrict__ excl,
                          const int* __restrict__ cnt,
                          const unsigned short* __restrict__ asrc2b, const float* __restrict__ adst2,
                          const unsigned short* __restrict__ h2b, float* __restrict__ agg2, int N) {
    int tid = blockIdx.x * 256 + threadIdx.x;
    int wave = tid >> 6;
    int lane = threadIdx.x & 63;
    int q = lane >> 4;
    int l = lane & 15;
    int wid = wave * 4 + q;
    if (wid >= N) return;

    int beg = excl[wid];
    int cw  = cnt[wid];
    const int* sp = srcs + beg;
    float adn = adst2[wid];
    bool ld = l < 10;

    float m0 = LRELU(bf2f(asrc2b[wid]) + adn), d0 = 1.f;
    float a0 = ld ? bf2f(h2b[(size_t)wid * 10 + l]) : 0.f;
    float m1 = -INFINITY, d1 = 0.f, a1 = 0.f;
    float m2 = -INFINITY, d2 = 0.f, a2 = 0.f;
    float m3 = -INFINITY, d3 = 0.f, a3 = 0.f;

    int i = 0;
    for (; i + 4 <= cw; i += 4) {
        int s0 = sp[i], s1 = sp[i + 1], s2 = sp[i + 2], s3 = sp[i + 3];
        float e0 = LRELU(bf2f(asrc2b[s0]) + adn);
        float e1 = LRELU(bf2f(asrc2b[s1]) + adn);
        float e2 = LRELU(bf2f(asrc2b[s2]) + adn);
        float e3 = LRELU(bf2f(asrc2b[s3]) + adn);
        float g0 = ld ? bf2f(h2b[(size_t)s0 * 10 + l]) : 0.f;
        float g1 = ld ? bf2f(h2b[(size_t)s1 * 10 + l]) : 0.f;
        float g2 = ld ? bf2f(h2b[(size_t)s2 * 10 + l]) : 0.f;
        float g3 = ld ? bf2f(h2b[(size_t)s3 * 10 + l]) : 0.f;
        UPD1(m0, d0, a0, e0, g0);
        UPD1(m1, d1, a1, e1, g1);
        UPD1(m2, d2, a2, e2, g2);
        UPD1(m3, d3, a3, e3, g3);
    }
    for (; i < cw; ++i) {
        int s = sp[i];
        float ev = LRELU(bf2f(asrc2b[s]) + adn);
        float gv = ld ? bf2f(h2b[(size_t)s * 10 + l]) : 0.f;
        UPD1(m0, d0, a0, ev, gv);
    }
    float mM = fmaxf(fmaxf(m0, m1), fmaxf(m2, m3));
    float w0 = fexp2(m0 - mM), w1 = fexp2(m1 - mM);
    float w2 = fexp2(m2 - mM), w3 = fexp2(m3 - mM);
    float den = d0 * w0 + d1 * w1 + d2 * w2 + d3 * w3;
    float acc = a0 * w0 + a1 * w1 + a2 * w2 + a3 * w3;
    if (ld) agg2[(size_t)wid * 10 + l] = acc / (den + 1e-16f);
}

// ---------------- pool (+bias) + log_softmax; block per graph ----------------
__global__ void k_pool_final(const float* __restrict__ agg2, const float* __restrict__ b2,
                             const int* __restrict__ batch, float* __restrict__ out,
                             int N, int G) {
    int g = blockIdx.x;
    int lo = 0, hi = N;
    while (lo < hi) { int mid = (lo + hi) >> 1; if (batch[mid] < g) lo = mid + 1; else hi = mid; }
    int s = lo;
    lo = s; hi = N;
    while (lo < hi) { int mid = (lo + hi) >> 1; if (batch[mid] < g + 1) lo = mid + 1; else hi = mid; }
    int e = lo;
    int tid = threadIdx.x;
    float acc[10];
#pragma unroll
    for (int j = 0; j < 10; ++j) acc[j] = 0.f;
    for (int n = s + tid; n < e; n += 256) {
        const float* r = agg2 + (size_t)n * 10;
#pragma unroll
        for (int j = 0; j < 10; ++j) acc[j] += r[j];
    }
    __shared__ float red[256 * 10];
#pragma unroll
    for (int j = 0; j < 10; ++j) red[tid * 10 + j] = acc[j];
    __syncthreads();
    for (int st = 128; st > 0; st >>= 1) {
        if (tid < st)
#pragma unroll
            for (int j = 0; j < 10; ++j) red[tid * 10 + j] += red[(tid + st) * 10 + j];
        __syncthreads();
    }
    if (tid == 0) {
        int c = e - s;
        float v[10], m = -1e30f;
#pragma unroll
        for (int j = 0; j < 10; ++j) {
            v[j] = (c > 0) ? red[j] / (float)c + b2[j] : 0.f;
            m = fmaxf(m, v[j]);
        }
        float ssum = 0.f;
#pragma unroll
        for (int j = 0; j < 10; ++j) ssum += expf(v[j] - m);
        float ls = logf(ssum);
#pragma unroll
        for (int j = 0; j < 10; ++j) out[(size_t)g * 10 + j] = v[j] - m - ls;
    }
}

extern "C" void kernel_launch(void* const* d_in, const int* in_sizes, int n_in,
                              void* d_out, int out_size, void* d_ws, size_t ws_size,
                              hipStream_t stream) {
    const float* x     = (const float*)d_in[0];
    const int*   ei    = (const int*)d_in[1];
    const int*   batch = (const int*)d_in[2];
    const float* W1    = (const float*)d_in[3];
    const float* as1w  = (const float*)d_in[4];
    const float* ad1w  = (const float*)d_in[5];
    const float* b1    = (const float*)d_in[6];
    const float* W2    = (const float*)d_in[7];
    const float* as2w  = (const float*)d_in[8];
    const float* ad2w  = (const float*)d_in[9];
    const float* b2    = (const float*)d_in[10];

    const int N  = in_sizes[0] / 128;
    const int E  = in_sizes[1] / 2;
    const int G  = out_size / 10;
    const int* srcE = ei;
    const int* dstE = ei + E;

    auto cdiv = [](long long a, long long b) { return (int)((a + b - 1) / b); };
    const int NB = cdiv(E, CH);

    // ---- workspace layout ----
    size_t Nz = (size_t)N;
    unsigned short* h1b = (unsigned short*)d_ws;        // N*64 bf16
    float* agg2  = (float*)d_ws;                        // ALIAS: h1b dead after gather1
    unsigned short* asrc1b = h1b + Nz * 64;             // N*8 bf16
    float* adst1 = (float*)(asrc1b + Nz * 8);           // N*8 f32
    unsigned short* h2b = (unsigned short*)(adst1 + Nz * 8); // N*10 bf16
    unsigned short* asrc2b = h2b + Nz * 10;             // N bf16
    float* adst2 = (float*)(asrc2b + Nz + (Nz & 1));    // N f32 (align 4B)
    float* agg1  = adst2 + Nz;                          // N*64 f32
    int2*  pairs = (int2*)agg1;                         // ALIAS: dead before gather1 writes agg1
    int* cntA    = (int*)(agg1 + Nz * 64);              // N
    int* exclA   = cntA + Nz;                           // N
    int* srcsA   = exclA + Nz;                          // E
    int* bhA     = srcsA + E;                           // 512*NB
    int* pstartA = bhA + (size_t)512 * NB;              // 512*NB
    int* totalA  = pstartA + (size_t)512 * NB;          // 512
    int* boffA   = totalA + 512;                        // 512

    const int B = 256;

    // layer-1 GEMM (+alpha dots): W-in-LDS, 4 nodes/thread, 128 nodes/block
    k_gemm1<<<cdiv(N, 128), B, 0, stream>>>(x, W1, as1w, ad1w, h1b, asrc1b, adst1, N);

    // graph-bucket CSR build (no global atomics)
    k_bhist<<<NB, B, 0, stream>>>(dstE, batch, E, NB, G, bhA);
    k_mscan<<<512, 512, 0, stream>>>(bhA, NB, pstartA, totalA);
    k_scan_top<<<1, 1024, 0, stream>>>(totalA, G, boffA);
    k_bscatter<<<NB, B, 0, stream>>>(srcE, dstE, batch, boffA, pstartA, E, NB, G, pairs);
    k_csr_local<<<G, 512, 0, stream>>>(pairs, boffA, batch, E, N, G, cntA, exclA, srcsA);

    // layer 1 gather: 16 nodes/block (4/wave), 4ch/lane
    k_gather1<<<cdiv(N, 16), B, 0, stream>>>(srcsA, exclA, cntA, asrc1b, adst1, h1b, agg1, N);
    k_fin1<<<cdiv(N, B), B, 0, stream>>>(agg1, b1, W2, as2w, ad2w, h2b, asrc2b, adst2, N);

    // layer 2 gather (agg2 aliases dead h1b)
    k_gather2<<<cdiv(N, 16), B, 0, stream>>>(srcsA, exclA, cntA, asrc2b, adst2, h2b, agg2, N);

    // pool + log_softmax
    k_pool_final<<<G, B, 0, stream>>>(agg2, b2, batch, (float*)d_out, N, G);
}

// Round 13
// 207.561 us; speedup vs baseline: 1.0850x; 1.0308x over previous
//
#include <hip/hip_runtime.h>
#include <math.h>

#define L2E 1.44269504088896f
#define LRELU(v) fmaxf((v), 0.2f * (v))

__device__ __forceinline__ float fexp2(float v) { return __builtin_amdgcn_exp2f(v); }

// bf16 helpers (RNE pack, exact unpack)
__device__ __forceinline__ unsigned short f2bf(float f) {
    unsigned u = __float_as_uint(f);
    u += 0x7FFFu + ((u >> 16) & 1u);
    return (unsigned short)(u >> 16);
}
__device__ __forceinline__ float bf2f(unsigned short b) {
    return __uint_as_float((unsigned)b << 16);
}

typedef __attribute__((ext_vector_type(8))) short bf16x8;
typedef __attribute__((ext_vector_type(4))) float f32x4;

// base-2 online-softmax update, 4 channels (float4 acc)
#define UPD4(mm, dd, AA, ev, GG)           \
    {                                      \
        float mn_ = fmaxf(mm, ev);         \
        float sc_ = fexp2(mm - mn_);       \
        float w_  = fexp2(ev - mn_);       \
        dd = dd * sc_ + w_;                \
        AA.x = AA.x * sc_ + w_ * (GG).x;   \
        AA.y = AA.y * sc_ + w_ * (GG).y;   \
        AA.z = AA.z * sc_ + w_ * (GG).z;   \
        AA.w = AA.w * sc_ + w_ * (GG).w;   \
        mm = mn_;                          \
    }
#define UPD1(mm, dd, aa, ev, hv)           \
    {                                      \
        float mn_ = fmaxf(mm, ev);         \
        float sc_ = fexp2(mm - mn_);       \
        float w_  = fexp2(ev - mn_);       \
        dd = dd * sc_ + w_;                \
        aa = aa * sc_ + w_ * (hv);         \
        mm = mn_;                          \
    }

#define CH 4096   // edges per bucket-build block

__device__ __forceinline__ float4 b4f(ushort4 u) {
    float4 r;
    r.x = bf2f(u.x); r.y = bf2f(u.y); r.z = bf2f(u.z); r.w = bf2f(u.w);
    return r;
}

// ---------------- layer-1 GEMM via MFMA: h1[n][64] = x[n][128] @ W[128][64] ----------------
// Wave = 16-node x 16-col tile; K=128 = 4x mfma_f32_16x16x32_bf16.
// A: row i = lane&15, k = (lane>>4)*8 + j (intra-lane k-order bijection-invariant
//    since B uses the same map). B: col = lane&15, same k map.
// C/D (m89-verified): col = lane&15, row = (lane>>4)*4 + r.
// W fragments in registers (loaded once per block, inline f32->bf16); zero LDS.
__global__ __launch_bounds__(256) void k_gemm1_mfma(
        const float* __restrict__ x, const float* __restrict__ W,
        unsigned short* __restrict__ h1b, int N, int ntiles) {
    int tid = threadIdx.x;
    int w = tid >> 6, l = tid & 63;
    int c0 = w * 16;              // wave's col group
    int lr = l & 15;              // A row / B,D col
    int lg = l >> 4;              // k/row group

    // B fragments: W[kk*32 + lg*8 + j][c0 + lr]
    bf16x8 bfr[4];
#pragma unroll
    for (int kk = 0; kk < 4; ++kk)
#pragma unroll
        for (int j = 0; j < 8; ++j)
            bfr[kk][j] = (short)f2bf(W[(size_t)(kk * 32 + lg * 8 + j) * 64 + c0 + lr]);

    for (int t = blockIdx.x; t < ntiles; t += gridDim.x) {
        int n0 = t * 16;
        int n = n0 + lr;
        const float4* xr = (const float4*)(x + (size_t)(n < N ? n : 0) * 128);
        f32x4 acc = {0.f, 0.f, 0.f, 0.f};
#pragma unroll
        for (int kk = 0; kk < 4; ++kk) {
            float4 u0 = xr[kk * 8 + lg * 2];
            float4 u1 = xr[kk * 8 + lg * 2 + 1];
            bf16x8 afr;
            afr[0] = (short)f2bf(u0.x); afr[1] = (short)f2bf(u0.y);
            afr[2] = (short)f2bf(u0.z); afr[3] = (short)f2bf(u0.w);
            afr[4] = (short)f2bf(u1.x); afr[5] = (short)f2bf(u1.y);
            afr[6] = (short)f2bf(u1.z); afr[7] = (short)f2bf(u1.w);
            acc = __builtin_amdgcn_mfma_f32_16x16x32_bf16(afr, bfr[kk], acc, 0, 0, 0);
        }
#pragma unroll
        for (int r = 0; r < 4; ++r) {
            int nn = n0 + lg * 4 + r;
            if (nn < N) h1b[(size_t)nn * 64 + c0 + lr] = f2bf(acc[r]);
        }
    }
}

// alpha dots from bf16 h1: thread per (n, h)
__global__ void k_alpha(const unsigned short* __restrict__ h1b,
                        const float* __restrict__ a_src, const float* __restrict__ a_dst,
                        unsigned short* __restrict__ asrcb, float* __restrict__ adst, int N) {
    int t = blockIdx.x * 256 + threadIdx.x;
    if (t >= N * 8) return;
    int n = t >> 3, h = t & 7;
    uint4 hw = *(const uint4*)&h1b[(size_t)n * 64 + h * 8];
    const unsigned short* hu = (const unsigned short*)&hw;
    const float* as = a_src + h * 8;
    const float* ad = a_dst + h * 8;
    float s = 0.f, d = 0.f;
#pragma unroll
    for (int c = 0; c < 8; ++c) {
        float hv = bf2f(hu[c]);
        s = fmaf(hv, as[c], s);
        d = fmaf(hv, ad[c], d);
    }
    asrcb[t] = f2bf(s * L2E);
    adst[t] = d * L2E;
}

// ---------------- graph-bucket sort (zero global atomics) ----------------

__global__ __launch_bounds__(256) void k_bhist(const int* __restrict__ dstE,
                                               const int* __restrict__ batch,
                                               int E, int NB, int G, int* __restrict__ bh) {
    __shared__ int lh[512];
    int tid = threadIdx.x, b = blockIdx.x;
    lh[tid] = 0; lh[tid + 256] = 0;
    __syncthreads();
#pragma unroll
    for (int i = 0; i < CH / 256; ++i) {
        int e = b * CH + i * 256 + tid;
        if (e < E) atomicAdd(&lh[batch[dstE[e]]], 1);
    }
    __syncthreads();
    if (tid < G)       bh[(size_t)tid * NB + b] = lh[tid];
    if (tid + 256 < G) bh[(size_t)(tid + 256) * NB + b] = lh[tid + 256];
}

__global__ __launch_bounds__(512) void k_mscan(const int* __restrict__ bh, int NB,
                                               int* __restrict__ pstart, int* __restrict__ total) {
    __shared__ int buf[512];
    int bin = blockIdx.x, t = threadIdx.x;
    int v = (t < NB) ? bh[(size_t)bin * NB + t] : 0;
    buf[t] = v;
    __syncthreads();
    for (int off = 1; off < 512; off <<= 1) {
        int u = (t >= off) ? buf[t - off] : 0;
        __syncthreads();
        buf[t] += u;
        __syncthreads();
    }
    if (t < NB) pstart[(size_t)bin * NB + t] = buf[t] - v;
    if (t == 511) total[bin] = buf[511];
}

__global__ __launch_bounds__(1024) void k_scan_top(const int* __restrict__ total, int nb,
                                                   int* __restrict__ boff) {
    __shared__ int buf[1024];
    int t = threadIdx.x;
    int v = (t < nb) ? total[t] : 0;
    buf[t] = v;
    __syncthreads();
    for (int off = 1; off < 1024; off <<= 1) {
        int u = (t >= off) ? buf[t - off] : 0;
        __syncthreads();
        buf[t] += u;
        __syncthreads();
    }
    if (t < nb) boff[t] = buf[t] - v;
}

__global__ __launch_bounds__(256) void k_bscatter(const int* __restrict__ srcE,
                                                  const int* __restrict__ dstE,
                                                  const int* __restrict__ batch,
                                                  const int* __restrict__ boff,
                                                  const int* __restrict__ pstart,
                                                  int E, int NB, int G, int2* __restrict__ pairs) {
    __shared__ int lstart[512];
    __shared__ int lc[512];
    int tid = threadIdx.x, b = blockIdx.x;
#pragma unroll
    for (int j = tid; j < 512; j += 256) {
        lstart[j] = (j < G) ? boff[j] + pstart[(size_t)j * NB + b] : 0;
        lc[j] = 0;
    }
    __syncthreads();
#pragma unroll
    for (int i = 0; i < CH / 256; ++i) {
        int e = b * CH + i * 256 + tid;
        if (e < E) {
            int s = srcE[e], d = dstE[e];
            int bin = batch[d];
            int old = atomicAdd(&lc[bin], 1);
            pairs[lstart[bin] + old] = make_int2(s, d);
        }
    }
}

__global__ __launch_bounds__(512) void k_csr_local(const int2* __restrict__ pairs,
                                                   const int* __restrict__ boff,
                                                   const int* __restrict__ batch,
                                                   int E, int N, int G,
                                                   int* __restrict__ cnt, int* __restrict__ excl,
                                                   int* __restrict__ srcs) {
    __shared__ int lcnt[512];
    __shared__ int buf[512];
    __shared__ int lcur[512];
    int g = blockIdx.x, t = threadIdx.x;
    int lo = 0, hi = N;
    while (lo < hi) { int mid = (lo + hi) >> 1; if (batch[mid] < g) lo = mid + 1; else hi = mid; }
    int ns = lo;
    hi = N;
    while (lo < hi) { int mid = (lo + hi) >> 1; if (batch[mid] < g + 1) lo = mid + 1; else hi = mid; }
    int ne = lo;
    int lnodes = ne - ns;
    int es = boff[g];
    int ee = (g + 1 < G) ? boff[g + 1] : E;

    lcnt[t] = 0;
    __syncthreads();
    for (int e = es + t; e < ee; e += 512) atomicAdd(&lcnt[pairs[e].y - ns], 1);
    __syncthreads();
    int v = lcnt[t];
    buf[t] = v;
    __syncthreads();
    for (int off = 1; off < 512; off <<= 1) {
        int u = (t >= off) ? buf[t - off] : 0;
        __syncthreads();
        buf[t] += u;
        __syncthreads();
    }
    int lex = buf[t] - v;
    lcur[t] = lex;
    if (t < lnodes) {
        cnt[ns + t] = v;
        excl[ns + t] = es + lex;
    }
    __syncthreads();
    for (int e = es + t; e < ee; e += 512) {
        int2 p = pairs[e];
        int pos = atomicAdd(&lcur[p.y - ns], 1);
        srcs[es + pos] = p.x;
    }
}

// ---------------- layer 1 gather: 4 nodes/wave, 16 lanes/node, bf16x4/lane ----------------
__global__ void k_gather1(const int* __restrict__ srcs, const int* __restrict__ excl,
                          const int* __restrict__ cnt,
                          const unsigned short* __restrict__ asrcb, const float* __restrict__ adst1,
                          const unsigned short* __restrict__ h1b, float* __restrict__ agg, int N) {
    int tid = blockIdx.x * 256 + threadIdx.x;
    int wave = tid >> 6;
    int lane = threadIdx.x & 63;
    int q = lane >> 4;            // node slot
    int l = lane & 15;
    int wid = wave * 4 + q;
    if (wid >= N) return;
    int h = l >> 1;               // head (2 lanes/head)
    int c0 = l * 4;               // channels c0..c0+3

    int beg = excl[wid];
    int cw  = cnt[wid];
    const int* sp = srcs + beg;
    float adh = adst1[wid * 8 + h];

    // self-loop init on chain 0
    float4 A0 = b4f(*(const ushort4*)&h1b[(size_t)wid * 64 + c0]);
    float m0 = LRELU(bf2f(asrcb[wid * 8 + h]) + adh), d0 = 1.f;
    float4 A1 = {0.f, 0.f, 0.f, 0.f}, A2 = A1, A3 = A1;
    float m1 = -INFINITY, d1 = 0.f;
    float m2 = -INFINITY, d2 = 0.f;
    float m3 = -INFINITY, d3 = 0.f;

    int i = 0;
    for (; i + 4 <= cw; i += 4) {
        int s0 = sp[i], s1 = sp[i + 1], s2 = sp[i + 2], s3 = sp[i + 3];
        float e0 = LRELU(bf2f(asrcb[s0 * 8 + h]) + adh);
        float e1 = LRELU(bf2f(asrcb[s1 * 8 + h]) + adh);
        float e2 = LRELU(bf2f(asrcb[s2 * 8 + h]) + adh);
        float e3 = LRELU(bf2f(asrcb[s3 * 8 + h]) + adh);
        float4 g0 = b4f(*(const ushort4*)&h1b[(size_t)s0 * 64 + c0]);
        float4 g1 = b4f(*(const ushort4*)&h1b[(size_t)s1 * 64 + c0]);
        float4 g2 = b4f(*(const ushort4*)&h1b[(size_t)s2 * 64 + c0]);
        float4 g3 = b4f(*(const ushort4*)&h1b[(size_t)s3 * 64 + c0]);
        UPD4(m0, d0, A0, e0, g0);
        UPD4(m1, d1, A1, e1, g1);
        UPD4(m2, d2, A2, e2, g2);
        UPD4(m3, d3, A3, e3, g3);
    }
    for (; i < cw; ++i) {
        int s = sp[i];
        float ev = LRELU(bf2f(asrcb[s * 8 + h]) + adh);
        float4 gv = b4f(*(const ushort4*)&h1b[(size_t)s * 64 + c0]);
        UPD4(m0, d0, A0, ev, gv);
    }
    float mM = fmaxf(fmaxf(m0, m1), fmaxf(m2, m3));
    float w0 = fexp2(m0 - mM), w1 = fexp2(m1 - mM);
    float w2 = fexp2(m2 - mM), w3 = fexp2(m3 - mM);
    float den = d0 * w0 + d1 * w1 + d2 * w2 + d3 * w3;
    float inv = 1.f / (den + 1e-16f);
    float4 r;
    r.x = (A0.x * w0 + A1.x * w1 + A2.x * w2 + A3.x * w3) * inv;
    r.y = (A0.y * w0 + A1.y * w1 + A2.y * w2 + A3.y * w3) * inv;
    r.z = (A0.z * w0 + A1.z * w1 + A2.z * w2 + A3.z * w3) * inv;
    r.w = (A0.w * w0 + A1.w * w1 + A2.w * w2 + A3.w * w3) * inv;
    *(float4*)&agg[(size_t)wid * 64 + c0] = r;
}

// out1 = elu(agg + b1); h2 = out1 @ W2 (64x10) -> bf16; layer-2 alpha dots (x log2e)
__global__ void k_fin1(const float* __restrict__ agg, const float* __restrict__ b1,
                       const float* __restrict__ W2,
                       const float* __restrict__ a_src2, const float* __restrict__ a_dst2,
                       unsigned short* __restrict__ h2b, unsigned short* __restrict__ asrc2b,
                       float* __restrict__ adst2, int N) {
    int n = blockIdx.x * 256 + threadIdx.x;
    if (n >= N) return;
    float acc[10];
#pragma unroll
    for (int j = 0; j < 10; ++j) acc[j] = 0.f;
    const float* ar = agg + (size_t)n * 64;
#pragma unroll 8
    for (int k = 0; k < 64; ++k) {
        float r = ar[k] + b1[k];
        r = r > 0.f ? r : expm1f(r);   // elu
#pragma unroll
        for (int j = 0; j < 10; ++j) acc[j] = fmaf(r, W2[k * 10 + j], acc[j]);
    }
    float s = 0.f, d = 0.f;
    unsigned pw[5];
#pragma unroll
    for (int j = 0; j < 10; j += 2) {
        s = fmaf(acc[j], a_src2[j], s);     d = fmaf(acc[j], a_dst2[j], d);
        s = fmaf(acc[j+1], a_src2[j+1], s); d = fmaf(acc[j+1], a_dst2[j+1], d);
        pw[j >> 1] = (unsigned)f2bf(acc[j]) | ((unsigned)f2bf(acc[j+1]) << 16);
    }
    unsigned* hw = (unsigned*)&h2b[(size_t)n * 10];
#pragma unroll
    for (int j = 0; j < 5; ++j) hw[j] = pw[j];
    asrc2b[n] = f2bf(s * L2E);
    adst2[n] = d * L2E;
}

// ---------------- layer 2 gather: 4 nodes/wave, 16 lanes/node ----------------
__global__ void k_gather2(const int* __restrict__ srcs, const int* __restrict__ excl,
                          const int* __restrict__ cnt,
                          const unsigned short* __restrict__ asrc2b, const float* __restrict__ adst2,
                          const unsigned short* __restrict__ h2b, float* __restrict__ agg2, int N) {
    int tid = blockIdx.x * 256 + threadIdx.x;
    int wave = tid >> 6;
    int lane = threadIdx.x & 63;
    int q = lane >> 4;
    int l = lane & 15;
    int wid = wave * 4 + q;
    if (wid >= N) return;

    int beg = excl[wid];
    int cw  = cnt[wid];
    const int* sp = srcs + beg;
    float adn = adst2[wid];
    bool ld = l < 10;

    float m0 = LRELU(bf2f(asrc2b[wid]) + adn), d0 = 1.f;
    float a0 = ld ? bf2f(h2b[(size_t)wid * 10 + l]) : 0.f;
    float m1 = -INFINITY, d1 = 0.f, a1 = 0.f;
    float m2 = -INFINITY, d2 = 0.f, a2 = 0.f;
    float m3 = -INFINITY, d3 = 0.f, a3 = 0.f;

    int i = 0;
    for (; i + 4 <= cw; i += 4) {
        int s0 = sp[i], s1 = sp[i + 1], s2 = sp[i + 2], s3 = sp[i + 3];
        float e0 = LRELU(bf2f(asrc2b[s0]) + adn);
        float e1 = LRELU(bf2f(asrc2b[s1]) + adn);
        float e2 = LRELU(bf2f(asrc2b[s2]) + adn);
        float e3 = LRELU(bf2f(asrc2b[s3]) + adn);
        float g0 = ld ? bf2f(h2b[(size_t)s0 * 10 + l]) : 0.f;
        float g1 = ld ? bf2f(h2b[(size_t)s1 * 10 + l]) : 0.f;
        float g2 = ld ? bf2f(h2b[(size_t)s2 * 10 + l]) : 0.f;
        float g3 = ld ? bf2f(h2b[(size_t)s3 * 10 + l]) : 0.f;
        UPD1(m0, d0, a0, e0, g0);
        UPD1(m1, d1, a1, e1, g1);
        UPD1(m2, d2, a2, e2, g2);
        UPD1(m3, d3, a3, e3, g3);
    }
    for (; i < cw; ++i) {
        int s = sp[i];
        float ev = LRELU(bf2f(asrc2b[s]) + adn);
        float gv = ld ? bf2f(h2b[(size_t)s * 10 + l]) : 0.f;
        UPD1(m0, d0, a0, ev, gv);
    }
    float mM = fmaxf(fmaxf(m0, m1), fmaxf(m2, m3));
    float w0 = fexp2(m0 - mM), w1 = fexp2(m1 - mM);
    float w2 = fexp2(m2 - mM), w3 = fexp2(m3 - mM);
    float den = d0 * w0 + d1 * w1 + d2 * w2 + d3 * w3;
    float acc = a0 * w0 + a1 * w1 + a2 * w2 + a3 * w3;
    if (ld) agg2[(size_t)wid * 10 + l] = acc / (den + 1e-16f);
}

// ---------------- pool (+bias) + log_softmax; block per graph ----------------
__global__ void k_pool_final(const float* __restrict__ agg2, const float* __restrict__ b2,
                             const int* __restrict__ batch, float* __restrict__ out,
                             int N, int G) {
    int g = blockIdx.x;
    int lo = 0, hi = N;
    while (lo < hi) { int mid = (lo + hi) >> 1; if (batch[mid] < g) lo = mid + 1; else hi = mid; }
    int s = lo;
    lo = s; hi = N;
    while (lo < hi) { int mid = (lo + hi) >> 1; if (batch[mid] < g + 1) lo = mid + 1; else hi = mid; }
    int e = lo;
    int tid = threadIdx.x;
    float acc[10];
#pragma unroll
    for (int j = 0; j < 10; ++j) acc[j] = 0.f;
    for (int n = s + tid; n < e; n += 256) {
        const float* r = agg2 + (size_t)n * 10;
#pragma unroll
        for (int j = 0; j < 10; ++j) acc[j] += r[j];
    }
    __shared__ float red[256 * 10];
#pragma unroll
    for (int j = 0; j < 10; ++j) red[tid * 10 + j] = acc[j];
    __syncthreads();
    for (int st = 128; st > 0; st >>= 1) {
        if (tid < st)
#pragma unroll
            for (int j = 0; j < 10; ++j) red[tid * 10 + j] += red[(tid + st) * 10 + j];
        __syncthreads();
    }
    if (tid == 0) {
        int c = e - s;
        float v[10], m = -1e30f;
#pragma unroll
        for (int j = 0; j < 10; ++j) {
            v[j] = (c > 0) ? red[j] / (float)c + b2[j] : 0.f;
            m = fmaxf(m, v[j]);
        }
        float ssum = 0.f;
#pragma unroll
        for (int j = 0; j < 10; ++j) ssum += expf(v[j] - m);
        float ls = logf(ssum);
#pragma unroll
        for (int j = 0; j < 10; ++j) out[(size_t)g * 10 + j] = v[j] - m - ls;
    }
}

extern "C" void kernel_launch(void* const* d_in, const int* in_sizes, int n_in,
                              void* d_out, int out_size, void* d_ws, size_t ws_size,
                              hipStream_t stream) {
    const float* x     = (const float*)d_in[0];
    const int*   ei    = (const int*)d_in[1];
    const int*   batch = (const int*)d_in[2];
    const float* W1    = (const float*)d_in[3];
    const float* as1w  = (const float*)d_in[4];
    const float* ad1w  = (const float*)d_in[5];
    const float* b1    = (const float*)d_in[6];
    const float* W2    = (const float*)d_in[7];
    const float* as2w  = (const float*)d_in[8];
    const float* ad2w  = (const float*)d_in[9];
    const float* b2    = (const float*)d_in[10];

    const int N  = in_sizes[0] / 128;
    const int E  = in_sizes[1] / 2;
    const int G  = out_size / 10;
    const int* srcE = ei;
    const int* dstE = ei + E;

    auto cdiv = [](long long a, long long b) { return (int)((a + b - 1) / b); };
    const int NB = cdiv(E, CH);

    // ---- workspace layout ----
    size_t Nz = (size_t)N;
    unsigned short* h1b = (unsigned short*)d_ws;        // N*64 bf16
    float* agg2  = (float*)d_ws;                        // ALIAS: h1b dead after gather1
    unsigned short* asrc1b = h1b + Nz * 64;             // N*8 bf16
    float* adst1 = (float*)(asrc1b + Nz * 8);           // N*8 f32
    unsigned short* h2b = (unsigned short*)(adst1 + Nz * 8); // N*10 bf16
    unsigned short* asrc2b = h2b + Nz * 10;             // N bf16
    float* adst2 = (float*)(asrc2b + Nz + (Nz & 1));    // N f32 (align 4B)
    float* agg1  = adst2 + Nz;                          // N*64 f32
    int2*  pairs = (int2*)agg1;                         // ALIAS: dead before gather1 writes agg1
    int* cntA    = (int*)(agg1 + Nz * 64);              // N
    int* exclA   = cntA + Nz;                           // N
    int* srcsA   = exclA + Nz;                          // E
    int* bhA     = srcsA + E;                           // 512*NB
    int* pstartA = bhA + (size_t)512 * NB;              // 512*NB
    int* totalA  = pstartA + (size_t)512 * NB;          // 512
    int* boffA   = totalA + 512;                        // 512

    const int B = 256;

    // layer-1 GEMM via MFMA (grid-stride over 16-node tiles), then alpha dots
    int ntiles = cdiv(N, 16);
    int gB = ntiles < 2048 ? ntiles : 2048;
    k_gemm1_mfma<<<gB, B, 0, stream>>>(x, W1, h1b, N, ntiles);
    k_alpha<<<cdiv((long long)N * 8, B), B, 0, stream>>>(h1b, as1w, ad1w, asrc1b, adst1, N);

    // graph-bucket CSR build (no global atomics)
    k_bhist<<<NB, B, 0, stream>>>(dstE, batch, E, NB, G, bhA);
    k_mscan<<<512, 512, 0, stream>>>(bhA, NB, pstartA, totalA);
    k_scan_top<<<1, 1024, 0, stream>>>(totalA, G, boffA);
    k_bscatter<<<NB, B, 0, stream>>>(srcE, dstE, batch, boffA, pstartA, E, NB, G, pairs);
    k_csr_local<<<G, 512, 0, stream>>>(pairs, boffA, batch, E, N, G, cntA, exclA, srcsA);

    // layer 1 gather: 16 nodes/block (4/wave), 4ch/lane
    k_gather1<<<cdiv(N, 16), B, 0, stream>>>(srcsA, exclA, cntA, asrc1b, adst1, h1b, agg1, N);
    k_fin1<<<cdiv(N, B), B, 0, stream>>>(agg1, b1, W2, as2w, ad2w, h2b, asrc2b, adst2, N);

    // layer 2 gather (agg2 aliases dead h1b)
    k_gather2<<<cdiv(N, 16), B, 0, stream>>>(srcsA, exclA, cntA, asrc2b, adst2, h2b, agg2, N);

    // pool + log_softmax
    k_pool_final<<<G, B, 0, stream>>>(agg2, b2, batch, (float*)d_out, N, G);
}

// Round 14
// 199.549 us; speedup vs baseline: 1.1285x; 1.0402x over previous
//
#include <hip/hip_runtime.h>
#include <math.h>

#define L2E 1.44269504088896f
#define LRELU(v) fmaxf((v), 0.2f * (v))

__device__ __forceinline__ float fexp2(float v) { return __builtin_amdgcn_exp2f(v); }

// bf16 helpers (RNE pack, exact unpack)
__device__ __forceinline__ unsigned short f2bf(float f) {
    unsigned u = __float_as_uint(f);
    u += 0x7FFFu + ((u >> 16) & 1u);
    return (unsigned short)(u >> 16);
}
__device__ __forceinline__ float bf2f(unsigned short b) {
    return __uint_as_float((unsigned)b << 16);
}

typedef __attribute__((ext_vector_type(8))) short bf16x8;
typedef __attribute__((ext_vector_type(4))) float f32x4;

// base-2 online-softmax update, 8 channels packed in uint4 (bf16 pairs)
#define UPD8(mm, dd, Aa, Ab, ev, U)                                       \
    {                                                                     \
        float mn_ = fmaxf(mm, ev);                                        \
        float sc_ = fexp2(mm - mn_);                                      \
        float w_  = fexp2(ev - mn_);                                      \
        dd = dd * sc_ + w_;                                               \
        Aa.x = Aa.x * sc_ + w_ * __uint_as_float((U).x << 16);            \
        Aa.y = Aa.y * sc_ + w_ * __uint_as_float((U).x & 0xffff0000u);    \
        Aa.z = Aa.z * sc_ + w_ * __uint_as_float((U).y << 16);            \
        Aa.w = Aa.w * sc_ + w_ * __uint_as_float((U).y & 0xffff0000u);    \
        Ab.x = Ab.x * sc_ + w_ * __uint_as_float((U).z << 16);            \
        Ab.y = Ab.y * sc_ + w_ * __uint_as_float((U).z & 0xffff0000u);    \
        Ab.z = Ab.z * sc_ + w_ * __uint_as_float((U).w << 16);            \
        Ab.w = Ab.w * sc_ + w_ * __uint_as_float((U).w & 0xffff0000u);    \
        mm = mn_;                                                         \
    }
#define UPD1(mm, dd, aa, ev, hv)           \
    {                                      \
        float mn_ = fmaxf(mm, ev);         \
        float sc_ = fexp2(mm - mn_);       \
        float w_  = fexp2(ev - mn_);       \
        dd = dd * sc_ + w_;                \
        aa = aa * sc_ + w_ * (hv);         \
        mm = mn_;                          \
    }

#define CH 4096   // edges per histogram block

// ---------------- fat kernel: layer-1 MFMA GEMM ∥ graph histogram ----------------
// GEMM: wave = 16-node x 16-col tile; K=128 = 4x mfma_f32_16x16x32_bf16; W frags
// in registers, zero LDS. Hist blocks (appended to grid) do LDS-only counting.
__global__ __launch_bounds__(256) void k_gemm1_hist(
        const float* __restrict__ x, const float* __restrict__ W,
        unsigned short* __restrict__ h1b, int N, int ntiles, int gemmBlocks,
        const int* __restrict__ dstE, const int* __restrict__ batch,
        int E, int NB, int G, int* __restrict__ bh) {
    __shared__ int lh[512];
    if ((int)blockIdx.x >= gemmBlocks) {
        // ---- histogram part ----
        int tid = threadIdx.x, b = blockIdx.x - gemmBlocks;
        lh[tid] = 0; lh[tid + 256] = 0;
        __syncthreads();
#pragma unroll
        for (int i = 0; i < CH / 256; ++i) {
            int e = b * CH + i * 256 + tid;
            if (e < E) atomicAdd(&lh[batch[dstE[e]]], 1);
        }
        __syncthreads();
        if (tid < G)       bh[(size_t)tid * NB + b] = lh[tid];
        if (tid + 256 < G) bh[(size_t)(tid + 256) * NB + b] = lh[tid + 256];
        return;
    }
    // ---- MFMA GEMM part ----
    int tid = threadIdx.x;
    int w = tid >> 6, l = tid & 63;
    int c0 = w * 16;
    int lr = l & 15;
    int lg = l >> 4;

    bf16x8 bfr[4];
#pragma unroll
    for (int kk = 0; kk < 4; ++kk)
#pragma unroll
        for (int j = 0; j < 8; ++j)
            bfr[kk][j] = (short)f2bf(W[(size_t)(kk * 32 + lg * 8 + j) * 64 + c0 + lr]);

    for (int t = blockIdx.x; t < ntiles; t += gemmBlocks) {
        int n0 = t * 16;
        int n = n0 + lr;
        const float4* xr = (const float4*)(x + (size_t)(n < N ? n : 0) * 128);
        f32x4 acc = {0.f, 0.f, 0.f, 0.f};
#pragma unroll
        for (int kk = 0; kk < 4; ++kk) {
            float4 u0 = xr[kk * 8 + lg * 2];
            float4 u1 = xr[kk * 8 + lg * 2 + 1];
            bf16x8 afr;
            afr[0] = (short)f2bf(u0.x); afr[1] = (short)f2bf(u0.y);
            afr[2] = (short)f2bf(u0.z); afr[3] = (short)f2bf(u0.w);
            afr[4] = (short)f2bf(u1.x); afr[5] = (short)f2bf(u1.y);
            afr[6] = (short)f2bf(u1.z); afr[7] = (short)f2bf(u1.w);
            acc = __builtin_amdgcn_mfma_f32_16x16x32_bf16(afr, bfr[kk], acc, 0, 0, 0);
        }
#pragma unroll
        for (int r = 0; r < 4; ++r) {
            int nn = n0 + lg * 4 + r;
            if (nn < N) h1b[(size_t)nn * 64 + c0 + lr] = f2bf(acc[r]);
        }
    }
}

// alpha dots from bf16 h1: thread per (n, h)
__global__ void k_alpha(const unsigned short* __restrict__ h1b,
                        const float* __restrict__ a_src, const float* __restrict__ a_dst,
                        unsigned short* __restrict__ asrcb, float* __restrict__ adst, int N) {
    int t = blockIdx.x * 256 + threadIdx.x;
    if (t >= N * 8) return;
    int n = t >> 3, h = t & 7;
    uint4 hw = *(const uint4*)&h1b[(size_t)n * 64 + h * 8];
    const unsigned short* hu = (const unsigned short*)&hw;
    const float* as = a_src + h * 8;
    const float* ad = a_dst + h * 8;
    float s = 0.f, d = 0.f;
#pragma unroll
    for (int c = 0; c < 8; ++c) {
        float hv = bf2f(hu[c]);
        s = fmaf(hv, as[c], s);
        d = fmaf(hv, ad[c], d);
    }
    asrcb[t] = f2bf(s * L2E);
    adst[t] = d * L2E;
}

// ---------------- CSR build (scan + scatter) ----------------

__global__ __launch_bounds__(512) void k_mscan(const int* __restrict__ bh, int NB,
                                               int* __restrict__ pstart, int* __restrict__ total) {
    __shared__ int buf[512];
    int bin = blockIdx.x, t = threadIdx.x;
    int v = (t < NB) ? bh[(size_t)bin * NB + t] : 0;
    buf[t] = v;
    __syncthreads();
    for (int off = 1; off < 512; off <<= 1) {
        int u = (t >= off) ? buf[t - off] : 0;
        __syncthreads();
        buf[t] += u;
        __syncthreads();
    }
    if (t < NB) pstart[(size_t)bin * NB + t] = buf[t] - v;
    if (t == 511) total[bin] = buf[511];
}

__global__ __launch_bounds__(1024) void k_scan_top(const int* __restrict__ total, int nb,
                                                   int* __restrict__ boff) {
    __shared__ int buf[1024];
    int t = threadIdx.x;
    int v = (t < nb) ? total[t] : 0;
    buf[t] = v;
    __syncthreads();
    for (int off = 1; off < 1024; off <<= 1) {
        int u = (t >= off) ? buf[t - off] : 0;
        __syncthreads();
        buf[t] += u;
        __syncthreads();
    }
    if (t < nb) boff[t] = buf[t] - v;
}

__global__ __launch_bounds__(256) void k_bscatter(const int* __restrict__ srcE,
                                                  const int* __restrict__ dstE,
                                                  const int* __restrict__ batch,
                                                  const int* __restrict__ boff,
                                                  const int* __restrict__ pstart,
                                                  int E, int NB, int G, int2* __restrict__ pairs) {
    __shared__ int lstart[512];
    __shared__ int lc[512];
    int tid = threadIdx.x, b = blockIdx.x;
#pragma unroll
    for (int j = tid; j < 512; j += 256) {
        lstart[j] = (j < G) ? boff[j] + pstart[(size_t)j * NB + b] : 0;
        lc[j] = 0;
    }
    __syncthreads();
#pragma unroll
    for (int i = 0; i < CH / 256; ++i) {
        int e = b * CH + i * 256 + tid;
        if (e < E) {
            int s = srcE[e], d = dstE[e];
            int bin = batch[d];
            int old = atomicAdd(&lc[bin], 1);
            pairs[lstart[bin] + old] = make_int2(s, d);
        }
    }
}

__global__ __launch_bounds__(512) void k_csr_local(const int2* __restrict__ pairs,
                                                   const int* __restrict__ boff,
                                                   const int* __restrict__ batch,
                                                   int E, int N, int G,
                                                   int* __restrict__ cnt, int* __restrict__ excl,
                                                   int* __restrict__ srcs) {
    __shared__ int lcnt[512];
    __shared__ int buf[512];
    __shared__ int lcur[512];
    int g = blockIdx.x, t = threadIdx.x;
    int lo = 0, hi = N;
    while (lo < hi) { int mid = (lo + hi) >> 1; if (batch[mid] < g) lo = mid + 1; else hi = mid; }
    int ns = lo;
    hi = N;
    while (lo < hi) { int mid = (lo + hi) >> 1; if (batch[mid] < g + 1) lo = mid + 1; else hi = mid; }
    int ne = lo;
    int lnodes = ne - ns;
    int es = boff[g];
    int ee = (g + 1 < G) ? boff[g + 1] : E;

    lcnt[t] = 0;
    __syncthreads();
    for (int e = es + t; e < ee; e += 512) atomicAdd(&lcnt[pairs[e].y - ns], 1);
    __syncthreads();
    int v = lcnt[t];
    buf[t] = v;
    __syncthreads();
    for (int off = 1; off < 512; off <<= 1) {
        int u = (t >= off) ? buf[t - off] : 0;
        __syncthreads();
        buf[t] += u;
        __syncthreads();
    }
    int lex = buf[t] - v;
    lcur[t] = lex;
    if (t < lnodes) {
        cnt[ns + t] = v;
        excl[ns + t] = es + lex;
    }
    __syncthreads();
    for (int e = es + t; e < ee; e += 512) {
        int2 p = pairs[e];
        int pos = atomicAdd(&lcur[p.y - ns], 1);
        srcs[es + pos] = p.x;
    }
}

// ---------------- layer 1 gather: 8 nodes/wave, 8 lanes/node, 8ch/lane ----------------
__global__ void k_gather1(const int* __restrict__ srcs, const int* __restrict__ excl,
                          const int* __restrict__ cnt,
                          const unsigned short* __restrict__ asrcb, const float* __restrict__ adst1,
                          const unsigned short* __restrict__ h1b, float* __restrict__ agg, int N) {
    int tid = blockIdx.x * 256 + threadIdx.x;
    int wave = tid >> 6;
    int lane = threadIdx.x & 63;
    int q = lane >> 3;            // node slot 0..7
    int l = lane & 7;             // head == channel group
    int wid = wave * 8 + q;
    if (wid >= N) return;
    int c0 = l * 8;               // channels c0..c0+7

    int beg = excl[wid];
    int cw  = cnt[wid];
    const int* sp = srcs + beg;
    float adh = adst1[wid * 8 + l];

    // self-loop init on chain 0
    uint4 us = *(const uint4*)&h1b[(size_t)wid * 64 + c0];
    float4 A0a, A0b;
    A0a.x = __uint_as_float(us.x << 16); A0a.y = __uint_as_float(us.x & 0xffff0000u);
    A0a.z = __uint_as_float(us.y << 16); A0a.w = __uint_as_float(us.y & 0xffff0000u);
    A0b.x = __uint_as_float(us.z << 16); A0b.y = __uint_as_float(us.z & 0xffff0000u);
    A0b.z = __uint_as_float(us.w << 16); A0b.w = __uint_as_float(us.w & 0xffff0000u);
    float m0 = LRELU(bf2f(asrcb[wid * 8 + l]) + adh), d0 = 1.f;
    float4 Z = {0.f, 0.f, 0.f, 0.f};
    float4 A1a = Z, A1b = Z, A2a = Z, A2b = Z, A3a = Z, A3b = Z;
    float m1 = -INFINITY, d1 = 0.f;
    float m2 = -INFINITY, d2 = 0.f;
    float m3 = -INFINITY, d3 = 0.f;

    int i = 0;
    for (; i + 4 <= cw; i += 4) {
        int s0 = sp[i], s1 = sp[i + 1], s2 = sp[i + 2], s3 = sp[i + 3];
        float e0 = LRELU(bf2f(asrcb[s0 * 8 + l]) + adh);
        float e1 = LRELU(bf2f(asrcb[s1 * 8 + l]) + adh);
        float e2 = LRELU(bf2f(asrcb[s2 * 8 + l]) + adh);
        float e3 = LRELU(bf2f(asrcb[s3 * 8 + l]) + adh);
        uint4 u0 = *(const uint4*)&h1b[(size_t)s0 * 64 + c0];
        uint4 u1 = *(const uint4*)&h1b[(size_t)s1 * 64 + c0];
        uint4 u2 = *(const uint4*)&h1b[(size_t)s2 * 64 + c0];
        uint4 u3 = *(const uint4*)&h1b[(size_t)s3 * 64 + c0];
        UPD8(m0, d0, A0a, A0b, e0, u0);
        UPD8(m1, d1, A1a, A1b, e1, u1);
        UPD8(m2, d2, A2a, A2b, e2, u2);
        UPD8(m3, d3, A3a, A3b, e3, u3);
    }
    for (; i < cw; ++i) {
        int s = sp[i];
        float ev = LRELU(bf2f(asrcb[s * 8 + l]) + adh);
        uint4 uv = *(const uint4*)&h1b[(size_t)s * 64 + c0];
        UPD8(m0, d0, A0a, A0b, ev, uv);
    }
    float mM = fmaxf(fmaxf(m0, m1), fmaxf(m2, m3));
    float w0 = fexp2(m0 - mM), w1 = fexp2(m1 - mM);
    float w2 = fexp2(m2 - mM), w3 = fexp2(m3 - mM);
    float den = d0 * w0 + d1 * w1 + d2 * w2 + d3 * w3;
    float inv = 1.f / (den + 1e-16f);
    float4 Ra, Rb;
    Ra.x = (A0a.x * w0 + A1a.x * w1 + A2a.x * w2 + A3a.x * w3) * inv;
    Ra.y = (A0a.y * w0 + A1a.y * w1 + A2a.y * w2 + A3a.y * w3) * inv;
    Ra.z = (A0a.z * w0 + A1a.z * w1 + A2a.z * w2 + A3a.z * w3) * inv;
    Ra.w = (A0a.w * w0 + A1a.w * w1 + A2a.w * w2 + A3a.w * w3) * inv;
    Rb.x = (A0b.x * w0 + A1b.x * w1 + A2b.x * w2 + A3b.x * w3) * inv;
    Rb.y = (A0b.y * w0 + A1b.y * w1 + A2b.y * w2 + A3b.y * w3) * inv;
    Rb.z = (A0b.z * w0 + A1b.z * w1 + A2b.z * w2 + A3b.z * w3) * inv;
    Rb.w = (A0b.w * w0 + A1b.w * w1 + A2b.w * w2 + A3b.w * w3) * inv;
    *(float4*)&agg[(size_t)wid * 64 + c0] = Ra;
    *(float4*)&agg[(size_t)wid * 64 + c0 + 4] = Rb;
}

// out1 = elu(agg + b1); h2 = out1 @ W2 (64x10) -> bf16; layer-2 alpha dots (x log2e)
__global__ void k_fin1(const float* __restrict__ agg, const float* __restrict__ b1,
                       const float* __restrict__ W2,
                       const float* __restrict__ a_src2, const float* __restrict__ a_dst2,
                       unsigned short* __restrict__ h2b, unsigned short* __restrict__ asrc2b,
                       float* __restrict__ adst2, int N) {
    int n = blockIdx.x * 256 + threadIdx.x;
    if (n >= N) return;
    float acc[10];
#pragma unroll
    for (int j = 0; j < 10; ++j) acc[j] = 0.f;
    const float4* ar4 = (const float4*)(agg + (size_t)n * 64);
    const float4* b14 = (const float4*)b1;
#pragma unroll 4
    for (int kq = 0; kq < 16; ++kq) {
        float4 a4 = ar4[kq];
        float4 bq = b14[kq];
        float r[4];
        r[0] = a4.x + bq.x; r[1] = a4.y + bq.y;
        r[2] = a4.z + bq.z; r[3] = a4.w + bq.w;
#pragma unroll
        for (int t = 0; t < 4; ++t) {
            float rv = r[t] > 0.f ? r[t] : expm1f(r[t]);   // elu
            const float* wr = W2 + (kq * 4 + t) * 10;
#pragma unroll
            for (int j = 0; j < 10; ++j) acc[j] = fmaf(rv, wr[j], acc[j]);
        }
    }
    float s = 0.f, d = 0.f;
    unsigned pw[5];
#pragma unroll
    for (int j = 0; j < 10; j += 2) {
        s = fmaf(acc[j], a_src2[j], s);     d = fmaf(acc[j], a_dst2[j], d);
        s = fmaf(acc[j+1], a_src2[j+1], s); d = fmaf(acc[j+1], a_dst2[j+1], d);
        pw[j >> 1] = (unsigned)f2bf(acc[j]) | ((unsigned)f2bf(acc[j+1]) << 16);
    }
    unsigned* hw = (unsigned*)&h2b[(size_t)n * 10];
#pragma unroll
    for (int j = 0; j < 5; ++j) hw[j] = pw[j];
    asrc2b[n] = f2bf(s * L2E);
    adst2[n] = d * L2E;
}

// ---------------- layer 2 gather: 4 nodes/wave, 16 lanes/node ----------------
__global__ void k_gather2(const int* __restrict__ srcs, const int* __restrict__ excl,
                          const int* __restrict__ cnt,
                          const unsigned short* __restrict__ asrc2b, const float* __restrict__ adst2,
                          const unsigned short* __restrict__ h2b, float* __restrict__ agg2, int N) {
    int tid = blockIdx.x * 256 + threadIdx.x;
    int wave = tid >> 6;
    int lane = threadIdx.x & 63;
    int q = lane >> 4;
    int l = lane & 15;
    int wid = wave * 4 + q;
    if (wid >= N) return;

    int beg = excl[wid];
    int cw  = cnt[wid];
    const int* sp = srcs + beg;
    float adn = adst2[wid];
    bool ld = l < 10;

    float m0 = LRELU(bf2f(asrc2b[wid]) + adn), d0 = 1.f;
    float a0 = ld ? bf2f(h2b[(size_t)wid * 10 + l]) : 0.f;
    float m1 = -INFINITY, d1 = 0.f, a1 = 0.f;
    float m2 = -INFINITY, d2 = 0.f, a2 = 0.f;
    float m3 = -INFINITY, d3 = 0.f, a3 = 0.f;

    int i = 0;
    for (; i + 4 <= cw; i += 4) {
        int s0 = sp[i], s1 = sp[i + 1], s2 = sp[i + 2], s3 = sp[i + 3];
        float e0 = LRELU(bf2f(asrc2b[s0]) + adn);
        float e1 = LRELU(bf2f(asrc2b[s1]) + adn);
        float e2 = LRELU(bf2f(asrc2b[s2]) + adn);
        float e3 = LRELU(bf2f(asrc2b[s3]) + adn);
        float g0 = ld ? bf2f(h2b[(size_t)s0 * 10 + l]) : 0.f;
        float g1 = ld ? bf2f(h2b[(size_t)s1 * 10 + l]) : 0.f;
        float g2 = ld ? bf2f(h2b[(size_t)s2 * 10 + l]) : 0.f;
        float g3 = ld ? bf2f(h2b[(size_t)s3 * 10 + l]) : 0.f;
        UPD1(m0, d0, a0, e0, g0);
        UPD1(m1, d1, a1, e1, g1);
        UPD1(m2, d2, a2, e2, g2);
        UPD1(m3, d3, a3, e3, g3);
    }
    for (; i < cw; ++i) {
        int s = sp[i];
        float ev = LRELU(bf2f(asrc2b[s]) + adn);
        float gv = ld ? bf2f(h2b[(size_t)s * 10 + l]) : 0.f;
        UPD1(m0, d0, a0, ev, gv);
    }
    float mM = fmaxf(fmaxf(m0, m1), fmaxf(m2, m3));
    float w0 = fexp2(m0 - mM), w1 = fexp2(m1 - mM);
    float w2 = fexp2(m2 - mM), w3 = fexp2(m3 - mM);
    float den = d0 * w0 + d1 * w1 + d2 * w2 + d3 * w3;
    float acc = a0 * w0 + a1 * w1 + a2 * w2 + a3 * w3;
    if (ld) agg2[(size_t)wid * 10 + l] = acc / (den + 1e-16f);
}

// ---------------- pool (+bias) + log_softmax; block per graph ----------------
__global__ void k_pool_final(const float* __restrict__ agg2, const float* __restrict__ b2,
                             const int* __restrict__ batch, float* __restrict__ out,
                             int N, int G) {
    int g = blockIdx.x;
    int lo = 0, hi = N;
    while (lo < hi) { int mid = (lo + hi) >> 1; if (batch[mid] < g) lo = mid + 1; else hi = mid; }
    int s = lo;
    lo = s; hi = N;
    while (lo < hi) { int mid = (lo + hi) >> 1; if (batch[mid] < g + 1) lo = mid + 1; else hi = mid; }
    int e = lo;
    int tid = threadIdx.x;
    float acc[10];
#pragma unroll
    for (int j = 0; j < 10; ++j) acc[j] = 0.f;
    for (int n = s + tid; n < e; n += 256) {
        const float* r = agg2 + (size_t)n * 10;
#pragma unroll
        for (int j = 0; j < 10; ++j) acc[j] += r[j];
    }
    __shared__ float red[256 * 10];
#pragma unroll
    for (int j = 0; j < 10; ++j) red[tid * 10 + j] = acc[j];
    __syncthreads();
    for (int st = 128; st > 0; st >>= 1) {
        if (tid < st)
#pragma unroll
            for (int j = 0; j < 10; ++j) red[tid * 10 + j] += red[(tid + st) * 10 + j];
        __syncthreads();
    }
    if (tid == 0) {
        int c = e - s;
        float v[10], m = -1e30f;
#pragma unroll
        for (int j = 0; j < 10; ++j) {
            v[j] = (c > 0) ? red[j] / (float)c + b2[j] : 0.f;
            m = fmaxf(m, v[j]);
        }
        float ssum = 0.f;
#pragma unroll
        for (int j = 0; j < 10; ++j) ssum += expf(v[j] - m);
        float ls = logf(ssum);
#pragma unroll
        for (int j = 0; j < 10; ++j) out[(size_t)g * 10 + j] = v[j] - m - ls;
    }
}

extern "C" void kernel_launch(void* const* d_in, const int* in_sizes, int n_in,
                              void* d_out, int out_size, void* d_ws, size_t ws_size,
                              hipStream_t stream) {
    const float* x     = (const float*)d_in[0];
    const int*   ei    = (const int*)d_in[1];
    const int*   batch = (const int*)d_in[2];
    const float* W1    = (const float*)d_in[3];
    const float* as1w  = (const float*)d_in[4];
    const float* ad1w  = (const float*)d_in[5];
    const float* b1    = (const float*)d_in[6];
    const float* W2    = (const float*)d_in[7];
    const float* as2w  = (const float*)d_in[8];
    const float* ad2w  = (const float*)d_in[9];
    const float* b2    = (const float*)d_in[10];

    const int N  = in_sizes[0] / 128;
    const int E  = in_sizes[1] / 2;
    const int G  = out_size / 10;
    const int* srcE = ei;
    const int* dstE = ei + E;

    auto cdiv = [](long long a, long long b) { return (int)((a + b - 1) / b); };
    const int NB = cdiv(E, CH);

    // ---- workspace layout ----
    size_t Nz = (size_t)N;
    unsigned short* h1b = (unsigned short*)d_ws;        // N*64 bf16
    float* agg2  = (float*)d_ws;                        // ALIAS: h1b dead after gather1
    unsigned short* asrc1b = h1b + Nz * 64;             // N*8 bf16
    float* adst1 = (float*)(asrc1b + Nz * 8);           // N*8 f32
    unsigned short* h2b = (unsigned short*)(adst1 + Nz * 8); // N*10 bf16
    unsigned short* asrc2b = h2b + Nz * 10;             // N bf16
    float* adst2 = (float*)(asrc2b + Nz + (Nz & 1));    // N f32 (align 4B)
    float* agg1  = adst2 + Nz;                          // N*64 f32
    int2*  pairs = (int2*)agg1;                         // ALIAS: dead before gather1 writes agg1
    int* cntA    = (int*)(agg1 + Nz * 64);              // N
    int* exclA   = cntA + Nz;                           // N
    int* srcsA   = exclA + Nz;                          // E
    int* bhA     = srcsA + E;                           // 512*NB
    int* pstartA = bhA + (size_t)512 * NB;              // 512*NB
    int* totalA  = pstartA + (size_t)512 * NB;          // 512
    int* boffA   = totalA + 512;                        // 512

    const int B = 256;

    // layer-1 MFMA GEMM ∥ graph histogram (fat kernel)
    int ntiles = cdiv(N, 16);
    int gB = ntiles < 2048 ? ntiles : 2048;
    k_gemm1_hist<<<gB + NB, B, 0, stream>>>(x, W1, h1b, N, ntiles, gB,
                                            dstE, batch, E, NB, G, bhA);
    k_alpha<<<cdiv((long long)N * 8, B), B, 0, stream>>>(h1b, as1w, ad1w, asrc1b, adst1, N);

    // CSR build
    k_mscan<<<512, 512, 0, stream>>>(bhA, NB, pstartA, totalA);
    k_scan_top<<<1, 1024, 0, stream>>>(totalA, G, boffA);
    k_bscatter<<<NB, B, 0, stream>>>(srcE, dstE, batch, boffA, pstartA, E, NB, G, pairs);
    k_csr_local<<<G, 512, 0, stream>>>(pairs, boffA, batch, E, N, G, cntA, exclA, srcsA);

    // layer 1 gather: 32 nodes/block (8/wave), 8ch/lane
    k_gather1<<<cdiv(N, 32), B, 0, stream>>>(srcsA, exclA, cntA, asrc1b, adst1, h1b, agg1, N);
    k_fin1<<<cdiv(N, B), B, 0, stream>>>(agg1, b1, W2, as2w, ad2w, h2b, asrc2b, adst2, N);

    // layer 2 gather (agg2 aliases dead h1b)
    k_gather2<<<cdiv(N, 16), B, 0, stream>>>(srcsA, exclA, cntA, asrc2b, adst2, h2b, agg2, N);

    // pool + log_softmax
    k_pool_final<<<G, B, 0, stream>>>(agg2, b2, batch, (float*)d_out, N, G);
}